// Round 6
// baseline (165.320 us; speedup 1.0000x reference)
//
#include <hip/hip_runtime.h>

#define T_   16
#define B_   8
#define N_   8
#define H_   128
#define C_   32
#define HW_  256
#define TAR_ 145
#define G4H  512
#define MEMIN 8593
#define AK   8480   // padded K for MFMA path: 8192 conv + 128 shared + 145 tar + 15 zero
#define XGN  524288 // elements per xg buffer

typedef __attribute__((ext_vector_type(8))) short short8v;
typedef __attribute__((ext_vector_type(4))) float f32x4;
typedef __attribute__((ext_vector_type(4), aligned(4))) float f32x4u; // 4B-aligned vec load

__device__ __forceinline__ float bf2f(unsigned short u){
  return __uint_as_float(((unsigned int)u) << 16);
}
__device__ __forceinline__ unsigned short f2bf(float x){
  unsigned int b = __float_as_uint(x);
  return (unsigned short)((b + 0x7fffu + ((b >> 16) & 1u)) >> 16);
}
// pack two f32 -> two bf16 (round-nearest-ties-away) in one dword via v_perm_b32
__device__ __forceinline__ unsigned pkbf(float lo, float hi){
  return __builtin_amdgcn_perm(__float_as_uint(hi) + 0x8000u,
                               __float_as_uint(lo) + 0x8000u, 0x07060302u);
}
__device__ __forceinline__ float bflo(unsigned w){ return __uint_as_float(w << 16); }
__device__ __forceinline__ float bfhi(unsigned w){ return __uint_as_float(w & 0xffff0000u); }
__device__ __forceinline__ float sigf(float x){ return 1.f/(1.f + expf(-x)); }

// ---------------------------------------------------------------------------
// shared[h] = Wo_b[h] + sum_d Wv_b[d] * Wo_w[h,d]   (attention collapses)
// ---------------------------------------------------------------------------
__global__ void k_shared(const float* __restrict__ WvB, const float* __restrict__ WoW,
                         const float* __restrict__ WoB, float* __restrict__ sh){
  const int h = blockIdx.x, lane = threadIdx.x;
  float acc = 0.f;
  for(int d = lane; d < 896; d += 64) acc += WvB[d] * WoW[h*896 + d];
  for(int s = 32; s; s >>= 1) acc += __shfl_down(acc, s);
  if(lane == 0) sh[h] = acc + WoB[h];
}

// ---------------------------------------------------------------------------
// gate[tb,n,c] = sigmoid(td_b[n,c] + sum_{x<145} tar[tb,x]*td_w[n,c,x])
// ---------------------------------------------------------------------------
__global__ __launch_bounds__(256) void k_gate(const float* __restrict__ tar,
                                              const float* __restrict__ tdw,
                                              const float* __restrict__ tdb,
                                              float* __restrict__ gate){
  __shared__ float twS[32*145];
  __shared__ float taS[16*145];
  const int tb0 = blockIdx.x * 16, n = blockIdx.y, tid = threadIdx.x;
  for(int i = tid; i < 32*145; i += 256){
    int c = i / 145, x = i - c*145;
    twS[i] = tdw[(n*32 + c)*273 + x];
  }
  for(int i = tid; i < 16*145; i += 256)
    taS[i] = tar[tb0*145 + i];
  __syncthreads();
  for(int o = tid; o < 512; o += 256){
    int r = o >> 5, c = o & 31;
    float a = tdb[n*32 + c];
    const float* tr = &taS[r*145];
    const float* tw = &twS[c*145];
    for(int x = 0; x < 145; ++x) a += tr[x]*tw[x];
    gate[((tb0 + r)*N_ + n)*C_ + c] = 1.f/(1.f + expf(-a));
  }
}

// ---------------------------------------------------------------------------
// conv v2: grid (tb=128, n=8), 256 threads = hw.  img tile staged in LDS once;
// gate-weighted conv_w transposed [c][d] in LDS (broadcast f32x4 reads);
// 32 d-accumulators in registers -> VALU-bound near f32 floor.
// FIX (r6): tail writes [8192..8480) via strided loop — with 256 threads the
// old guard left tar[128..144] + zero-pad unwritten (round-5 absmax 0.16).
// ---------------------------------------------------------------------------
__global__ __launch_bounds__(256) void k_conv2(
    const float* __restrict__ img, const float* __restrict__ gate,
    const float* __restrict__ cw, const float* __restrict__ cb,
    const float* __restrict__ sh, const float* __restrict__ tar,
    unsigned short* __restrict__ mem)
{
  __shared__ float imgS[8192];    // [c][hw]
  __shared__ float cwgT[1024];    // [c][d] = cw[d][c]*gate[n][c]
  const int tb = blockIdx.x, n = blockIdx.y;
  const int hw = threadIdx.x;
  for(int i = hw; i < 8192; i += 256)
    imgS[i] = img[(size_t)tb*8192 + i];
  for(int i = hw; i < 1024; i += 256){
    const int c = i >> 5, d = i & 31;
    cwgT[i] = cw[d*32 + c] * gate[(tb*8 + n)*32 + c];
  }
  __syncthreads();
  f32x4 acc[8];
  #pragma unroll
  for(int dq = 0; dq < 8; ++dq){
    const f32x4u cv = *(const f32x4u*)&cb[dq*4];
    acc[dq].x = cv.x; acc[dq].y = cv.y; acc[dq].z = cv.z; acc[dq].w = cv.w;
  }
  #pragma unroll 4
  for(int c = 0; c < 32; ++c){
    const float iv = imgS[c*256 + hw];
    #pragma unroll
    for(int dq = 0; dq < 8; ++dq){
      const f32x4 w = *(const f32x4*)&cwgT[c*32 + dq*4];
      acc[dq].x += iv*w.x; acc[dq].y += iv*w.y;
      acc[dq].z += iv*w.z; acc[dq].w += iv*w.w;
    }
  }
  unsigned short* mrow = mem + (size_t)(n*128 + tb)*AK;
  #pragma unroll
  for(int dq = 0; dq < 8; ++dq){
    mrow[(dq*4 + 0)*256 + hw] = f2bf(acc[dq].x);
    mrow[(dq*4 + 1)*256 + hw] = f2bf(acc[dq].y);
    mrow[(dq*4 + 2)*256 + hw] = f2bf(acc[dq].z);
    mrow[(dq*4 + 3)*256 + hw] = f2bf(acc[dq].w);
  }
  for(int i = hw; i < 288; i += 256){
    if(i < 128)      mrow[8192 + i]       = f2bf(sh[i]);
    else if(i < 273) mrow[8320 + i - 128] = f2bf(tar[tb*TAR_ + i - 128]);
    else             mrow[8465 + i - 273] = 0;
  }
}

// ---------------------------------------------------------------------------
// MFMA GEMM v3: grid (32 gt, 8 n, 4 ks), block 4 waves; block tile 128r x 16g,
// wave tile 32r x 16g.  Explicit 1-deep software prefetch (load k+32 while
// MFMA on k); epilogue iter without prefetch (no OOB).  launch_bounds(256,4)
// -> <=128 VGPR, 16 waves/CU.  K-splits write 4 disjoint buffers.
// C/D: col=lane&15, row=(lane>>4)*4+j  (HW-verified layout).
// ---------------------------------------------------------------------------
__global__ __launch_bounds__(256, 4) void k_gemm3(
    const unsigned short* __restrict__ mem, const float* __restrict__ Wih,
    float* __restrict__ xg4)
{
  const int gt = blockIdx.x, n = blockIdx.y, ks = blockIdx.z;
  const int wv = threadIdx.x >> 6, ln = threadIdx.x & 63;
  const int lr = ln & 15, lg = ln >> 4;
  const int g0 = gt*16;
  const int kbeg = ks*2112;
  const int kend = (ks == 3) ? AK : kbeg + 2112;
  const int iters = (kend - kbeg) >> 5;       // 66 or 67
  const float* Bp = Wih + (size_t)(n*G4H + g0 + lr)*MEMIN + lg*8 + kbeg;
  const unsigned short* Ap0 = mem + (size_t)(n*128 + wv*32 + lr)*AK + lg*8 + kbeg;
  const unsigned short* Ap1 = Ap0 + (size_t)16*AK;
  f32x4 acc0 = {0.f,0.f,0.f,0.f};
  f32x4 acc1 = {0.f,0.f,0.f,0.f};

  f32x4u bl = *(const f32x4u*)(Bp);
  f32x4u bh = *(const f32x4u*)(Bp + 4);
  short8v a0 = *(const short8v*)(Ap0);
  short8v a1 = *(const short8v*)(Ap1);

  for(int it = 0; it < iters - 1; ++it){
    const int kn = (it + 1) << 5;
    const f32x4u blN = *(const f32x4u*)(Bp + kn);
    const f32x4u bhN = *(const f32x4u*)(Bp + kn + 4);
    const short8v a0N = *(const short8v*)(Ap0 + kn);
    const short8v a1N = *(const short8v*)(Ap1 + kn);
    short8v bf;
    unsigned* u = (unsigned*)&bf;
    u[0] = pkbf(bl.x, bl.y); u[1] = pkbf(bl.z, bl.w);
    u[2] = pkbf(bh.x, bh.y); u[3] = pkbf(bh.z, bh.w);
    acc0 = __builtin_amdgcn_mfma_f32_16x16x32_bf16(a0, bf, acc0, 0, 0, 0);
    acc1 = __builtin_amdgcn_mfma_f32_16x16x32_bf16(a1, bf, acc1, 0, 0, 0);
    bl = blN; bh = bhN; a0 = a0N; a1 = a1N;
  }
  {
    short8v bf;
    unsigned* u = (unsigned*)&bf;
    u[0] = pkbf(bl.x, bl.y); u[1] = pkbf(bl.z, bl.w);
    u[2] = pkbf(bh.x, bh.y); u[3] = pkbf(bh.z, bh.w);
    acc0 = __builtin_amdgcn_mfma_f32_16x16x32_bf16(a0, bf, acc0, 0, 0, 0);
    acc1 = __builtin_amdgcn_mfma_f32_16x16x32_bf16(a1, bf, acc1, 0, 0, 0);
  }

  float* dst = xg4 + (size_t)ks*XGN;
  const int c0 = g0 + lr;
  const int r0 = wv*32 + lg*4, r1 = r0 + 16;
  #pragma unroll
  for(int j = 0; j < 4; ++j){
    dst[(size_t)((r0 + j)*8 + n)*G4H + c0] = acc0[j];
    dst[(size_t)((r1 + j)*8 + n)*G4H + c0] = acc1[j];
  }
}

// ---------------------------------------------------------------------------
// LSTM v2: 64 blocks = (b,n) pairs, 512 threads = gate-row g.  Whh row held
// packed-bf16 in 64 VGPRs (loaded once).  Per step: sum 4 K-split xg buffers
// + bias, dot over broadcast h (LDS), activations by threads<128.
// ---------------------------------------------------------------------------
__global__ __launch_bounds__(512) void k_lstm2(
    const float* __restrict__ xg4, const float* __restrict__ Whh,
    const float* __restrict__ bih, const float* __restrict__ bhh,
    float* __restrict__ out)
{
  __shared__ float hS[128];
  __shared__ float preS[512];
  const int bn = blockIdx.x;
  const int n = bn & 7, b = bn >> 3;
  const int g = threadIdx.x;

  unsigned wr[64];
  const float* wrow = Whh + (size_t)(n*G4H + g)*H_;
  #pragma unroll
  for(int i = 0; i < 32; ++i){
    const f32x4 w = *(const f32x4*)(wrow + i*4);
    wr[2*i]   = pkbf(w.x, w.y);
    wr[2*i+1] = pkbf(w.z, w.w);
  }
  const float bias = bih[n*G4H + g] + bhh[n*G4H + g];
  if(g < 128) hS[g] = 0.f;
  float cc = 0.f;
  __syncthreads();

  for(int t = 0; t < 16; ++t){
    const size_t xb = (size_t)((t*8 + b)*8 + n)*G4H + g;
    float acc = bias + xg4[xb] + xg4[xb + XGN] + xg4[xb + 2*XGN] + xg4[xb + 3*XGN];
    #pragma unroll
    for(int q = 0; q < 32; ++q){
      const f32x4 hv = *(const f32x4*)&hS[q*4];
      const unsigned w0 = wr[2*q], w1 = wr[2*q+1];
      acc += hv.x*bflo(w0) + hv.y*bfhi(w0) + hv.z*bflo(w1) + hv.w*bfhi(w1);
    }
    preS[g] = acc;
    __syncthreads();
    if(g < 128){
      const float iv = sigf(preS[g]);
      const float fv = sigf(preS[128 + g]);
      const float gv = tanhf(preS[256 + g]);
      const float ov = sigf(preS[384 + g]);
      cc = fv*cc + iv*gv;
      const float hn = ov*tanhf(cc);
      hS[g] = hn;
      out[(t*8 + b)*1024 + n*128 + g] = hn;
      if(t == 15){
        out[131072 + (b*8 + n)*128 + g] = hn;   // hT
        out[139264 + (b*8 + n)*128 + g] = cc;   // cT
      }
    }
    __syncthreads();
  }
}

// ---------------------------------------------------------------------------
// Tier-B fallbacks (round-3 verified): conv v1 + bias init + atomic MFMA gemm
// + old lstm
// ---------------------------------------------------------------------------
__global__ __launch_bounds__(512) void k_conv(
    const float* __restrict__ img, const float* __restrict__ gate,
    const float* __restrict__ cw, const float* __restrict__ cb,
    const float* __restrict__ sh, const float* __restrict__ tar,
    unsigned short* __restrict__ mem)
{
  __shared__ float imgS[8192];
  __shared__ float cwgS[1024];
  __shared__ float shS[128];
  __shared__ float tarS[160];
  const int tb = blockIdx.x, tid = threadIdx.x;
  for(int i = tid; i < 8192; i += 512)
    imgS[i] = img[(size_t)tb*8192 + i];
  if(tid < 128) shS[tid] = sh[tid];
  if(tid >= 128 && tid < 273) tarS[tid-128] = tar[tb*TAR_ + tid - 128];
  for(int n = 0; n < 8; ++n){
    __syncthreads();
    for(int i = tid; i < 1024; i += 512)
      cwgS[i] = cw[i] * gate[(tb*8 + n)*32 + (i & 31)];
    __syncthreads();
    unsigned short* mrow = mem + (size_t)(n*128 + tb)*AK;
    for(int q = 0; q < 4; ++q){
      const int idx = q*2048 + tid*4;
      const int d = idx >> 8, hw = idx & 255;
      const float bias = cb[d];
      float a0 = bias, a1 = bias, a2 = bias, a3 = bias;
      const float* cg = &cwgS[d*32];
      #pragma unroll
      for(int c = 0; c < 32; ++c){
        const f32x4 iv = *(const f32x4*)&imgS[c*256 + hw];
        const float w = cg[c];
        a0 += w*iv.x; a1 += w*iv.y; a2 += w*iv.z; a3 += w*iv.w;
      }
      ushort4 o;
      o.x = f2bf(a0); o.y = f2bf(a1); o.z = f2bf(a2); o.w = f2bf(a3);
      *(ushort4*)&mrow[idx] = o;
    }
    if(tid < 128)      mrow[8192 + tid]       = f2bf(shS[tid]);
    else if(tid < 273) mrow[8320 + tid - 128] = f2bf(tarS[tid - 128]);
    else if(tid < 288) mrow[8465 + tid - 273] = 0;
  }
}

__global__ __launch_bounds__(256) void k_bias(const float* __restrict__ bih,
                                              const float* __restrict__ bhh,
                                              float* __restrict__ xg){
  const int i = blockIdx.x*256 + threadIdx.x;
  const int ng = ((i >> 9) & 7)*512 + (i & 511);
  xg[i] = bih[ng] + bhh[ng];
}

__global__ __launch_bounds__(256) void k_gemm_mfma(
    const unsigned short* __restrict__ mem, const float* __restrict__ Wih,
    float* __restrict__ xg)
{
  const int gt = blockIdx.x, n = blockIdx.y, ks = blockIdx.z;
  const int wv = threadIdx.x >> 6, ln = threadIdx.x & 63;
  const int lr = ln & 15, lg = ln >> 4;
  const int g0 = gt*16;
  const int kbeg = (ks==0) ? 0 : (ks==1) ? 2144 : (ks==2) ? 4256 : 6368;
  const int kend = (ks==0) ? 2144 : (ks==1) ? 4256 : (ks==2) ? 6368 : 8480;
  const float* Bp = Wih + (size_t)(n*G4H + g0 + lr)*MEMIN + lg*8;
  const unsigned short* Ap = mem + (size_t)(n*128 + wv*32 + lr)*AK + lg*8;
  f32x4 acc0 = {0.f,0.f,0.f,0.f};
  f32x4 acc1 = {0.f,0.f,0.f,0.f};
  #pragma unroll 2
  for(int k = kbeg; k < kend; k += 32){
    const f32x4u blo = *(const f32x4u*)(Bp + k);
    const f32x4u bhi = *(const f32x4u*)(Bp + k + 4);
    short8v bf;
    unsigned* bu = (unsigned*)&bf;
    bu[0] = pkbf(blo.x, blo.y); bu[1] = pkbf(blo.z, blo.w);
    bu[2] = pkbf(bhi.x, bhi.y); bu[3] = pkbf(bhi.z, bhi.w);
    const short8v a0 = *(const short8v*)(Ap + k);
    const short8v a1 = *(const short8v*)(Ap + (size_t)16*AK + k);
    acc0 = __builtin_amdgcn_mfma_f32_16x16x32_bf16(a0, bf, acc0, 0, 0, 0);
    acc1 = __builtin_amdgcn_mfma_f32_16x16x32_bf16(a1, bf, acc1, 0, 0, 0);
  }
  const int col = g0 + lr;
  const int r0  = wv*32 + lg*4;
  #pragma unroll
  for(int j = 0; j < 4; ++j){
    atomicAdd(&xg[(size_t)((r0 + j)*8 + n)*G4H + col],      acc0[j]);
    atomicAdd(&xg[(size_t)((r0 + 16 + j)*8 + n)*G4H + col], acc1[j]);
  }
}

__global__ __launch_bounds__(1024) void k_lstm(
    const float* __restrict__ xg, const float* __restrict__ Whh,
    float* __restrict__ out)
{
  extern __shared__ char smem[];
  unsigned short* Wl = (unsigned short*)smem;
  float* hS = (float*)(smem + 512*136*sizeof(unsigned short));

  const int n = blockIdx.x, tid = threadIdx.x;
  for(int i = tid; i < 512*128; i += 1024){
    int g = i >> 7, k = i & 127;
    Wl[g*136 + k] = f2bf(Whh[n*512*128 + i]);
  }
  hS[tid] = 0.f;
  const int h = tid >> 3, b = tid & 7;
  float cc = 0.f;
  __syncthreads();

  for(int t = 0; t < 16; ++t){
    const long xbase = ((long)((t*8 + b)*8 + n))*G4H + h;
    float g0 = xg[xbase + 0*128];
    float g1 = xg[xbase + 1*128];
    float g2 = xg[xbase + 2*128];
    float g3 = xg[xbase + 3*128];
    const float* hr = &hS[b*128];
    const unsigned short* w0 = &Wl[(0*128 + h)*136];
    const unsigned short* w1 = &Wl[(1*128 + h)*136];
    const unsigned short* w2 = &Wl[(2*128 + h)*136];
    const unsigned short* w3 = &Wl[(3*128 + h)*136];
    for(int k = 0; k < 128; k += 4){
      const float4 hv = *(const float4*)&hr[k];
      const ushort4 a0 = *(const ushort4*)&w0[k];
      const ushort4 a1 = *(const ushort4*)&w1[k];
      const ushort4 a2 = *(const ushort4*)&w2[k];
      const ushort4 a3 = *(const ushort4*)&w3[k];
      g0 += hv.x*bf2f(a0.x) + hv.y*bf2f(a0.y) + hv.z*bf2f(a0.z) + hv.w*bf2f(a0.w);
      g1 += hv.x*bf2f(a1.x) + hv.y*bf2f(a1.y) + hv.z*bf2f(a1.z) + hv.w*bf2f(a1.w);
      g2 += hv.x*bf2f(a2.x) + hv.y*bf2f(a2.y) + hv.z*bf2f(a2.z) + hv.w*bf2f(a2.w);
      g3 += hv.x*bf2f(a3.x) + hv.y*bf2f(a3.y) + hv.z*bf2f(a3.z) + hv.w*bf2f(a3.w);
    }
    const float iv = sigf(g0);
    const float fv = sigf(g1);
    const float gv = tanhf(g2);
    const float ov = sigf(g3);
    cc = fv*cc + iv*gv;
    const float hn = ov * tanhf(cc);
    __syncthreads();
    hS[b*128 + h] = hn;
    out[(t*8 + b)*1024 + n*128 + h] = hn;
    if(t == 15){
      out[131072 + (b*8 + n)*128 + h] = hn;
      out[139264 + (b*8 + n)*128 + h] = cc;
    }
    __syncthreads();
  }
}

// ---------------------------------------------------------------------------
// Tier-C fallback (round-2 verified, no extra ws): fused VALU gemm
// ---------------------------------------------------------------------------
__global__ __launch_bounds__(256) void k_gemm_old(
    const float* __restrict__ img, const float* __restrict__ gate,
    const float* __restrict__ cw, const float* __restrict__ cb,
    const float* __restrict__ sh, const float* __restrict__ tar,
    const float* __restrict__ Wih, const float* __restrict__ bih,
    const float* __restrict__ bhh, float* __restrict__ xg)
{
  __shared__ __align__(16) float imgS[16*545];
  __shared__ __align__(16) float WtS[16*132];
  __shared__ float PS[16*17];
  __shared__ float gateS[16*32];
  __shared__ float cw2S[16*32];
  __shared__ float cwS[32*32];
  __shared__ float cbS[32];
  __shared__ float shS[128];
  __shared__ float tarS[16*145];

  const int tid = threadIdx.x;
  const int g0  = blockIdx.x * 128;
  const int tb0 = blockIdx.y * 16;
  const int n   = blockIdx.z;
  const int gth = tid & 31;
  const int rth = tid >> 5;
  const long wbase = (long)(n*G4H + g0) * MEMIN;

  for(int i = tid; i < 16*32; i += 256){
    int r = i >> 5, c = i & 31;
    gateS[i] = gate[((tb0 + r)*N_ + n)*C_ + c];
  }
  for(int i = tid; i < 32*32; i += 256) cwS[i] = cw[i];
  if(tid < 32)  cbS[tid] = cb[tid];
  if(tid < 128) shS[tid] = sh[tid];
  for(int i = tid; i < 16*TAR_; i += 256)
    tarS[i] = tar[tb0*TAR_ + i];

  float acc0[4] = {0,0,0,0}, acc1[4] = {0,0,0,0};

  for(int s = 0; s < 16; ++s){
    __syncthreads();
    for(int i = tid; i < 8192; i += 256){
      int j = i & 15, c = (i >> 4) & 31, r = i >> 9;
      imgS[r*545 + c*17 + j] = img[((tb0 + r)*C_ + c)*HW_ + s*16 + j];
    }
    for(int d = 0; d < 32; ++d){
      __syncthreads();
      for(int i = tid; i < 2048; i += 256){
        int g = i >> 4, j = i & 15;
        WtS[j*132 + g] = Wih[wbase + (long)g*MEMIN + d*HW_ + s*16 + j];
      }
      for(int i = tid; i < 512; i += 256)
        cw2S[i] = gateS[i] * cwS[d*32 + (i & 31)];
      __syncthreads();
      {
        int j = tid & 15, r = tid >> 4;
        float a = cbS[d];
        const float* c2 = &cw2S[r*32];
        const float* im = &imgS[r*545 + j];
        #pragma unroll
        for(int c = 0; c < 32; ++c) a += c2[c] * im[c*17];
        PS[j*17 + r] = a;
      }
      __syncthreads();
      #pragma unroll
      for(int j = 0; j < 16; ++j){
        const float4 w = *(const float4*)&WtS[j*132 + (gth << 2)];
        const float p0 = PS[j*17 + (rth << 1)];
        const float p1 = PS[j*17 + (rth << 1) + 1];
        acc0[0] += p0*w.x; acc0[1] += p0*w.y; acc0[2] += p0*w.z; acc0[3] += p0*w.w;
        acc1[0] += p1*w.x; acc1[1] += p1*w.y; acc1[2] += p1*w.z; acc1[3] += p1*w.w;
      }
    }
  }
  {
    float ta[4] = {0,0,0,0};
    for(int kc = 0; kc < 8; ++kc){
      __syncthreads();
      for(int i = tid; i < 2048; i += 256){
        int g = i >> 4, j = i & 15;
        WtS[j*132 + g] = Wih[wbase + (long)g*MEMIN + 8192 + kc*16 + j];
      }
      __syncthreads();
      #pragma unroll
      for(int j = 0; j < 16; ++j){
        const float4 w = *(const float4*)&WtS[j*132 + (gth << 2)];
        const float sv = shS[kc*16 + j];
        ta[0] += sv*w.x; ta[1] += sv*w.y; ta[2] += sv*w.z; ta[3] += sv*w.w;
      }
    }
    acc0[0] += ta[0]; acc0[1] += ta[1]; acc0[2] += ta[2]; acc0[3] += ta[3];
    acc1[0] += ta[0]; acc1[1] += ta[1]; acc1[2] += ta[2]; acc1[3] += ta[3];
  }
  for(int kc = 0; kc < 10; ++kc){
    const int kendl = (kc == 9) ? 1 : 16;
    __syncthreads();
    for(int i = tid; i < 2048; i += 256){
      int g = i >> 4, j = i & 15;
      if(j < kendl)
        WtS[j*132 + g] = Wih[wbase + (long)g*MEMIN + 8320 + kc*16 + j];
    }
    __syncthreads();
    for(int j = 0; j < kendl; ++j){
      const float4 w = *(const float4*)&WtS[j*132 + (gth << 2)];
      const float p0 = tarS[(rth << 1)*TAR_ + kc*16 + j];
      const float p1 = tarS[((rth << 1) + 1)*TAR_ + kc*16 + j];
      acc0[0] += p0*w.x; acc0[1] += p0*w.y; acc0[2] += p0*w.z; acc0[3] += p0*w.w;
      acc1[0] += p1*w.x; acc1[1] += p1*w.y; acc1[2] += p1*w.z; acc1[3] += p1*w.w;
    }
  }
  {
    const int gg = g0 + (gth << 2);
    const float b0 = bih[n*G4H + gg + 0] + bhh[n*G4H + gg + 0];
    const float b1 = bih[n*G4H + gg + 1] + bhh[n*G4H + gg + 1];
    const float b2 = bih[n*G4H + gg + 2] + bhh[n*G4H + gg + 2];
    const float b3 = bih[n*G4H + gg + 3] + bhh[n*G4H + gg + 3];
    const int row = tb0 + (rth << 1);
    float4 o0 = make_float4(acc0[0]+b0, acc0[1]+b1, acc0[2]+b2, acc0[3]+b3);
    *(float4*)&xg[((long)(row*N_ + n))*G4H + gg] = o0;
    float4 o1 = make_float4(acc1[0]+b0, acc1[1]+b1, acc1[2]+b2, acc1[3]+b3);
    *(float4*)&xg[((long)((row + 1)*N_ + n))*G4H + gg] = o1;
  }
}

// ---------------------------------------------------------------------------
extern "C" void kernel_launch(void* const* d_in, const int* in_sizes, int n_in,
                              void* d_out, int out_size, void* d_ws, size_t ws_size,
                              hipStream_t stream)
{
  (void)in_sizes; (void)n_in; (void)out_size;
  const float* img  = (const float*)d_in[0];
  const float* tar  = (const float*)d_in[1];
  const float* WvB  = (const float*)d_in[7];
  const float* WoW  = (const float*)d_in[8];
  const float* WoB  = (const float*)d_in[9];
  const float* tdw  = (const float*)d_in[10];
  const float* tdb  = (const float*)d_in[11];
  const float* cw   = (const float*)d_in[12];
  const float* cb   = (const float*)d_in[13];
  const float* Wih  = (const float*)d_in[14];
  const float* Whh  = (const float*)d_in[15];
  const float* bih  = (const float*)d_in[16];
  const float* bhh  = (const float*)d_in[17];

  float* wsf   = (float*)d_ws;
  float* gatew = wsf;                       // 32768 f
  float* shw   = wsf + 32768;               // 128 f

  // Tier A layout: xg4 @ f32[32896..2130048) (4 x 524288), mem @ byte 8520192
  float* xg4w = wsf + 32896;
  unsigned short* memA = (unsigned short*)((char*)d_ws + 8520192);
  const size_t WS_A = 8520192 + (size_t)8*128*AK*2;          // 25,887,232 B

  // Tier B layout (round-3): xg @ f32[32896..557184), mem @ byte 2228736
  float* xgB = wsf + 32896;
  unsigned short* memB = (unsigned short*)((char*)d_ws + 2228736);
  const size_t WS_B = 2228736 + (size_t)8*128*AK*2;          // 19,595,776 B

  k_shared<<<128, 64, 0, stream>>>(WvB, WoW, WoB, shw);
  k_gate<<<dim3(8, 8), 256, 0, stream>>>(tar, tdw, tdb, gatew);

  if(ws_size >= WS_A){
    k_conv2<<<dim3(128, 8), 256, 0, stream>>>(img, gatew, cw, cb, shw, tar, memA);
    k_gemm3<<<dim3(32, 8, 4), 256, 0, stream>>>(memA, Wih, xg4w);
    k_lstm2<<<64, 512, 0, stream>>>(xg4w, Whh, bih, bhh, (float*)d_out);
  } else if(ws_size >= WS_B){
    k_conv<<<128, 512, 0, stream>>>(img, gatew, cw, cb, shw, tar, memB);
    k_bias<<<2048, 256, 0, stream>>>(bih, bhh, xgB);
    k_gemm_mfma<<<dim3(32, 8, 4), 256, 0, stream>>>(memB, Wih, xgB);
    (void)hipFuncSetAttribute((const void*)k_lstm,
                              hipFuncAttributeMaxDynamicSharedMemorySize, 143360);
    k_lstm<<<8, 1024, 143360, stream>>>(xgB, Whh, (float*)d_out);
  } else {
    k_gemm_old<<<dim3(4, 8, 8), 256, 0, stream>>>(img, gatew, cw, cb, shw, tar,
                                                  Wih, bih, bhh, xgB);
    (void)hipFuncSetAttribute((const void*)k_lstm,
                              hipFuncAttributeMaxDynamicSharedMemorySize, 143360);
    k_lstm<<<8, 1024, 143360, stream>>>(xgB, Whh, (float*)d_out);
  }
}

// Round 7
// 163.323 us; speedup vs baseline: 1.0122x; 1.0122x over previous
//
#include <hip/hip_runtime.h>

#define T_   16
#define B_   8
#define N_   8
#define H_   128
#define C_   32
#define HW_  256
#define TAR_ 145
#define G4H  512
#define MEMIN 8593
#define AK   8480   // padded K for MFMA path: 8192 conv + 128 shared + 145 tar + 15 zero
#define XGN  524288 // elements per xg buffer

typedef __attribute__((ext_vector_type(8))) short short8v;
typedef __attribute__((ext_vector_type(4))) float f32x4;
typedef __attribute__((ext_vector_type(4), aligned(4))) float f32x4u; // 4B-aligned vec load

__device__ __forceinline__ float bf2f(unsigned short u){
  return __uint_as_float(((unsigned int)u) << 16);
}
__device__ __forceinline__ unsigned short f2bf(float x){
  unsigned int b = __float_as_uint(x);
  return (unsigned short)((b + 0x7fffu + ((b >> 16) & 1u)) >> 16);
}
// pack two f32 -> two bf16 (round-nearest-ties-away) in one dword via v_perm_b32
__device__ __forceinline__ unsigned pkbf(float lo, float hi){
  return __builtin_amdgcn_perm(__float_as_uint(hi) + 0x8000u,
                               __float_as_uint(lo) + 0x8000u, 0x07060302u);
}
__device__ __forceinline__ float bflo(unsigned w){ return __uint_as_float(w << 16); }
__device__ __forceinline__ float bfhi(unsigned w){ return __uint_as_float(w & 0xffff0000u); }
__device__ __forceinline__ float sigf(float x){ return 1.f/(1.f + expf(-x)); }

// ---------------------------------------------------------------------------
// shared[h] = Wo_b[h] + sum_d Wv_b[d] * Wo_w[h,d]   (attention collapses)
// ---------------------------------------------------------------------------
__global__ void k_shared(const float* __restrict__ WvB, const float* __restrict__ WoW,
                         const float* __restrict__ WoB, float* __restrict__ sh){
  const int h = blockIdx.x, lane = threadIdx.x;
  float acc = 0.f;
  for(int d = lane; d < 896; d += 64) acc += WvB[d] * WoW[h*896 + d];
  for(int s = 32; s; s >>= 1) acc += __shfl_down(acc, s);
  if(lane == 0) sh[h] = acc + WoB[h];
}

// ---------------------------------------------------------------------------
// gate[tb,n,c] = sigmoid(td_b[n,c] + sum_{x<145} tar[tb,x]*td_w[n,c,x])
// ---------------------------------------------------------------------------
__global__ __launch_bounds__(256) void k_gate(const float* __restrict__ tar,
                                              const float* __restrict__ tdw,
                                              const float* __restrict__ tdb,
                                              float* __restrict__ gate){
  __shared__ float twS[32*145];
  __shared__ float taS[16*145];
  const int tb0 = blockIdx.x * 16, n = blockIdx.y, tid = threadIdx.x;
  for(int i = tid; i < 32*145; i += 256){
    int c = i / 145, x = i - c*145;
    twS[i] = tdw[(n*32 + c)*273 + x];
  }
  for(int i = tid; i < 16*145; i += 256)
    taS[i] = tar[tb0*145 + i];
  __syncthreads();
  for(int o = tid; o < 512; o += 256){
    int r = o >> 5, c = o & 31;
    float a = tdb[n*32 + c];
    const float* tr = &taS[r*145];
    const float* tw = &twS[c*145];
    for(int x = 0; x < 145; ++x) a += tr[x]*tw[x];
    gate[((tb0 + r)*N_ + n)*C_ + c] = 1.f/(1.f + expf(-a));
  }
}

// ---------------------------------------------------------------------------
// conv v2: grid (tb=128, n=8), 256 threads = hw.  img tile staged in LDS once;
// gate-weighted conv_w transposed [c][d] in LDS (broadcast f32x4 reads);
// 32 d-accumulators in registers.  Tail [8192..8480) via strided loop.
// ---------------------------------------------------------------------------
__global__ __launch_bounds__(256) void k_conv2(
    const float* __restrict__ img, const float* __restrict__ gate,
    const float* __restrict__ cw, const float* __restrict__ cb,
    const float* __restrict__ sh, const float* __restrict__ tar,
    unsigned short* __restrict__ mem)
{
  __shared__ float imgS[8192];    // [c][hw]
  __shared__ float cwgT[1024];    // [c][d] = cw[d][c]*gate[n][c]
  const int tb = blockIdx.x, n = blockIdx.y;
  const int hw = threadIdx.x;
  for(int i = hw; i < 8192; i += 256)
    imgS[i] = img[(size_t)tb*8192 + i];
  for(int i = hw; i < 1024; i += 256){
    const int c = i >> 5, d = i & 31;
    cwgT[i] = cw[d*32 + c] * gate[(tb*8 + n)*32 + c];
  }
  __syncthreads();
  f32x4 acc[8];
  #pragma unroll
  for(int dq = 0; dq < 8; ++dq){
    const f32x4u cv = *(const f32x4u*)&cb[dq*4];
    acc[dq].x = cv.x; acc[dq].y = cv.y; acc[dq].z = cv.z; acc[dq].w = cv.w;
  }
  #pragma unroll 4
  for(int c = 0; c < 32; ++c){
    const float iv = imgS[c*256 + hw];
    #pragma unroll
    for(int dq = 0; dq < 8; ++dq){
      const f32x4 w = *(const f32x4*)&cwgT[c*32 + dq*4];
      acc[dq].x += iv*w.x; acc[dq].y += iv*w.y;
      acc[dq].z += iv*w.z; acc[dq].w += iv*w.w;
    }
  }
  unsigned short* mrow = mem + (size_t)(n*128 + tb)*AK;
  #pragma unroll
  for(int dq = 0; dq < 8; ++dq){
    mrow[(dq*4 + 0)*256 + hw] = f2bf(acc[dq].x);
    mrow[(dq*4 + 1)*256 + hw] = f2bf(acc[dq].y);
    mrow[(dq*4 + 2)*256 + hw] = f2bf(acc[dq].z);
    mrow[(dq*4 + 3)*256 + hw] = f2bf(acc[dq].w);
  }
  for(int i = hw; i < 288; i += 256){
    if(i < 128)      mrow[8192 + i]       = f2bf(sh[i]);
    else if(i < 273) mrow[8320 + i - 128] = f2bf(tar[tb*TAR_ + i - 128]);
    else             mrow[8465 + i - 273] = 0;
  }
}

// ---------------------------------------------------------------------------
// MFMA GEMM v4: grid (16 gt, 8 n, 4 ks), block = 8 waves (512 thr), block
// tile 128r x 32g; wave = 32r x 16g (wv&3 = row group, wv>>2 = g group).
// K chunked by 128: issue 4 iters' A/B loads into unrolled register arrays,
// sched_barrier(0) fence (scheduler cannot sink loads past it), then consume
// (pack f32->bf16 + 2 MFMA per iter).  Compiler emits counted vmcnt per use.
// ~40 vmem instrs / 256B per lane in flight per wave; 16 waves/CU.
// C/D: col=lane&15, row=(lane>>4)*4+j  (HW-verified layout).
// ---------------------------------------------------------------------------
__global__ __launch_bounds__(512) void k_gemm4(
    const unsigned short* __restrict__ mem, const float* __restrict__ Wih,
    float* __restrict__ xg4)
{
  const int gt = blockIdx.x, n = blockIdx.y, ks = blockIdx.z;
  const int wv = threadIdx.x >> 6, ln = threadIdx.x & 63;
  const int lr = ln & 15, lg = ln >> 4;
  const int rg = wv & 3;            // rows rg*32 .. rg*32+31
  const int g0 = gt*32 + (wv >> 2)*16;
  const int kbeg = ks*2112;
  const int kend = (ks == 3) ? AK : kbeg + 2112;
  const float* Bp = Wih + (size_t)(n*G4H + g0 + lr)*MEMIN + lg*8;
  const unsigned short* Ap0 = mem + (size_t)(n*128 + rg*32 + lr)*AK + lg*8;
  const unsigned short* Ap1 = Ap0 + (size_t)16*AK;
  f32x4 acc0 = {0.f,0.f,0.f,0.f};
  f32x4 acc1 = {0.f,0.f,0.f,0.f};

  int k = kbeg;
  for(; k + 128 <= kend; k += 128){
    f32x4u bl[4], bh[4];
    short8v a0[4], a1[4];
    #pragma unroll
    for(int it = 0; it < 4; ++it){
      const int kk = k + it*32;
      bl[it] = *(const f32x4u*)(Bp + kk);
      bh[it] = *(const f32x4u*)(Bp + kk + 4);
      a0[it] = *(const short8v*)(Ap0 + kk);
      a1[it] = *(const short8v*)(Ap1 + kk);
    }
    __builtin_amdgcn_sched_barrier(0);
    #pragma unroll
    for(int it = 0; it < 4; ++it){
      short8v bf;
      unsigned* u = (unsigned*)&bf;
      u[0] = pkbf(bl[it].x, bl[it].y); u[1] = pkbf(bl[it].z, bl[it].w);
      u[2] = pkbf(bh[it].x, bh[it].y); u[3] = pkbf(bh[it].z, bh[it].w);
      acc0 = __builtin_amdgcn_mfma_f32_16x16x32_bf16(a0[it], bf, acc0, 0, 0, 0);
      acc1 = __builtin_amdgcn_mfma_f32_16x16x32_bf16(a1[it], bf, acc1, 0, 0, 0);
    }
  }
  for(; k < kend; k += 32){
    const f32x4u bl = *(const f32x4u*)(Bp + k);
    const f32x4u bh = *(const f32x4u*)(Bp + k + 4);
    const short8v a0 = *(const short8v*)(Ap0 + k);
    const short8v a1 = *(const short8v*)(Ap1 + k);
    short8v bf;
    unsigned* u = (unsigned*)&bf;
    u[0] = pkbf(bl.x, bl.y); u[1] = pkbf(bl.z, bl.w);
    u[2] = pkbf(bh.x, bh.y); u[3] = pkbf(bh.z, bh.w);
    acc0 = __builtin_amdgcn_mfma_f32_16x16x32_bf16(a0, bf, acc0, 0, 0, 0);
    acc1 = __builtin_amdgcn_mfma_f32_16x16x32_bf16(a1, bf, acc1, 0, 0, 0);
  }

  float* dst = xg4 + (size_t)ks*XGN;
  const int c0 = g0 + lr;
  const int r0 = rg*32 + lg*4, r1 = r0 + 16;
  #pragma unroll
  for(int j = 0; j < 4; ++j){
    dst[(size_t)((r0 + j)*8 + n)*G4H + c0] = acc0[j];
    dst[(size_t)((r1 + j)*8 + n)*G4H + c0] = acc1[j];
  }
}

// ---------------------------------------------------------------------------
// LSTM v2: 64 blocks = (b,n) pairs, 512 threads = gate-row g.  Whh row held
// packed-bf16 in 64 VGPRs (loaded once).  Per step: sum 4 K-split xg buffers
// + bias, dot over broadcast h (LDS), activations by threads<128.
// ---------------------------------------------------------------------------
__global__ __launch_bounds__(512) void k_lstm2(
    const float* __restrict__ xg4, const float* __restrict__ Whh,
    const float* __restrict__ bih, const float* __restrict__ bhh,
    float* __restrict__ out)
{
  __shared__ float hS[128];
  __shared__ float preS[512];
  const int bn = blockIdx.x;
  const int n = bn & 7, b = bn >> 3;
  const int g = threadIdx.x;

  unsigned wr[64];
  const float* wrow = Whh + (size_t)(n*G4H + g)*H_;
  #pragma unroll
  for(int i = 0; i < 32; ++i){
    const f32x4 w = *(const f32x4*)(wrow + i*4);
    wr[2*i]   = pkbf(w.x, w.y);
    wr[2*i+1] = pkbf(w.z, w.w);
  }
  const float bias = bih[n*G4H + g] + bhh[n*G4H + g];
  if(g < 128) hS[g] = 0.f;
  float cc = 0.f;
  __syncthreads();

  for(int t = 0; t < 16; ++t){
    const size_t xb = (size_t)((t*8 + b)*8 + n)*G4H + g;
    float acc = bias + xg4[xb] + xg4[xb + XGN] + xg4[xb + 2*XGN] + xg4[xb + 3*XGN];
    #pragma unroll
    for(int q = 0; q < 32; ++q){
      const f32x4 hv = *(const f32x4*)&hS[q*4];
      const unsigned w0 = wr[2*q], w1 = wr[2*q+1];
      acc += hv.x*bflo(w0) + hv.y*bfhi(w0) + hv.z*bflo(w1) + hv.w*bfhi(w1);
    }
    preS[g] = acc;
    __syncthreads();
    if(g < 128){
      const float iv = sigf(preS[g]);
      const float fv = sigf(preS[128 + g]);
      const float gv = tanhf(preS[256 + g]);
      const float ov = sigf(preS[384 + g]);
      cc = fv*cc + iv*gv;
      const float hn = ov*tanhf(cc);
      hS[g] = hn;
      out[(t*8 + b)*1024 + n*128 + g] = hn;
      if(t == 15){
        out[131072 + (b*8 + n)*128 + g] = hn;   // hT
        out[139264 + (b*8 + n)*128 + g] = cc;   // cT
      }
    }
    __syncthreads();
  }
}

// ---------------------------------------------------------------------------
// Tier-B fallbacks (round-3 verified): conv v1 + bias init + atomic MFMA gemm
// + old lstm
// ---------------------------------------------------------------------------
__global__ __launch_bounds__(512) void k_conv(
    const float* __restrict__ img, const float* __restrict__ gate,
    const float* __restrict__ cw, const float* __restrict__ cb,
    const float* __restrict__ sh, const float* __restrict__ tar,
    unsigned short* __restrict__ mem)
{
  __shared__ float imgS[8192];
  __shared__ float cwgS[1024];
  __shared__ float shS[128];
  __shared__ float tarS[160];
  const int tb = blockIdx.x, tid = threadIdx.x;
  for(int i = tid; i < 8192; i += 512)
    imgS[i] = img[(size_t)tb*8192 + i];
  if(tid < 128) shS[tid] = sh[tid];
  if(tid >= 128 && tid < 273) tarS[tid-128] = tar[tb*TAR_ + tid - 128];
  for(int n = 0; n < 8; ++n){
    __syncthreads();
    for(int i = tid; i < 1024; i += 512)
      cwgS[i] = cw[i] * gate[(tb*8 + n)*32 + (i & 31)];
    __syncthreads();
    unsigned short* mrow = mem + (size_t)(n*128 + tb)*AK;
    for(int q = 0; q < 4; ++q){
      const int idx = q*2048 + tid*4;
      const int d = idx >> 8, hw = idx & 255;
      const float bias = cb[d];
      float a0 = bias, a1 = bias, a2 = bias, a3 = bias;
      const float* cg = &cwgS[d*32];
      #pragma unroll
      for(int c = 0; c < 32; ++c){
        const f32x4 iv = *(const f32x4*)&imgS[c*256 + hw];
        const float w = cg[c];
        a0 += w*iv.x; a1 += w*iv.y; a2 += w*iv.z; a3 += w*iv.w;
      }
      ushort4 o;
      o.x = f2bf(a0); o.y = f2bf(a1); o.z = f2bf(a2); o.w = f2bf(a3);
      *(ushort4*)&mrow[idx] = o;
    }
    if(tid < 128)      mrow[8192 + tid]       = f2bf(shS[tid]);
    else if(tid < 273) mrow[8320 + tid - 128] = f2bf(tarS[tid - 128]);
    else if(tid < 288) mrow[8465 + tid - 273] = 0;
  }
}

__global__ __launch_bounds__(256) void k_bias(const float* __restrict__ bih,
                                              const float* __restrict__ bhh,
                                              float* __restrict__ xg){
  const int i = blockIdx.x*256 + threadIdx.x;
  const int ng = ((i >> 9) & 7)*512 + (i & 511);
  xg[i] = bih[ng] + bhh[ng];
}

__global__ __launch_bounds__(256) void k_gemm_mfma(
    const unsigned short* __restrict__ mem, const float* __restrict__ Wih,
    float* __restrict__ xg)
{
  const int gt = blockIdx.x, n = blockIdx.y, ks = blockIdx.z;
  const int wv = threadIdx.x >> 6, ln = threadIdx.x & 63;
  const int lr = ln & 15, lg = ln >> 4;
  const int g0 = gt*16;
  const int kbeg = (ks==0) ? 0 : (ks==1) ? 2144 : (ks==2) ? 4256 : 6368;
  const int kend = (ks==0) ? 2144 : (ks==1) ? 4256 : (ks==2) ? 6368 : 8480;
  const float* Bp = Wih + (size_t)(n*G4H + g0 + lr)*MEMIN + lg*8;
  const unsigned short* Ap = mem + (size_t)(n*128 + wv*32 + lr)*AK + lg*8;
  f32x4 acc0 = {0.f,0.f,0.f,0.f};
  f32x4 acc1 = {0.f,0.f,0.f,0.f};
  #pragma unroll 2
  for(int k = kbeg; k < kend; k += 32){
    const f32x4u blo = *(const f32x4u*)(Bp + k);
    const f32x4u bhi = *(const f32x4u*)(Bp + k + 4);
    short8v bf;
    unsigned* bu = (unsigned*)&bf;
    bu[0] = pkbf(blo.x, blo.y); bu[1] = pkbf(blo.z, blo.w);
    bu[2] = pkbf(bhi.x, bhi.y); bu[3] = pkbf(bhi.z, bhi.w);
    const short8v a0 = *(const short8v*)(Ap + k);
    const short8v a1 = *(const short8v*)(Ap + (size_t)16*AK + k);
    acc0 = __builtin_amdgcn_mfma_f32_16x16x32_bf16(a0, bf, acc0, 0, 0, 0);
    acc1 = __builtin_amdgcn_mfma_f32_16x16x32_bf16(a1, bf, acc1, 0, 0, 0);
  }
  const int col = g0 + lr;
  const int r0  = wv*32 + lg*4;
  #pragma unroll
  for(int j = 0; j < 4; ++j){
    atomicAdd(&xg[(size_t)((r0 + j)*8 + n)*G4H + col],      acc0[j]);
    atomicAdd(&xg[(size_t)((r0 + 16 + j)*8 + n)*G4H + col], acc1[j]);
  }
}

__global__ __launch_bounds__(1024) void k_lstm(
    const float* __restrict__ xg, const float* __restrict__ Whh,
    float* __restrict__ out)
{
  extern __shared__ char smem[];
  unsigned short* Wl = (unsigned short*)smem;
  float* hS = (float*)(smem + 512*136*sizeof(unsigned short));

  const int n = blockIdx.x, tid = threadIdx.x;
  for(int i = tid; i < 512*128; i += 1024){
    int g = i >> 7, k = i & 127;
    Wl[g*136 + k] = f2bf(Whh[n*512*128 + i]);
  }
  hS[tid] = 0.f;
  const int h = tid >> 3, b = tid & 7;
  float cc = 0.f;
  __syncthreads();

  for(int t = 0; t < 16; ++t){
    const long xbase = ((long)((t*8 + b)*8 + n))*G4H + h;
    float g0 = xg[xbase + 0*128];
    float g1 = xg[xbase + 1*128];
    float g2 = xg[xbase + 2*128];
    float g3 = xg[xbase + 3*128];
    const float* hr = &hS[b*128];
    const unsigned short* w0 = &Wl[(0*128 + h)*136];
    const unsigned short* w1 = &Wl[(1*128 + h)*136];
    const unsigned short* w2 = &Wl[(2*128 + h)*136];
    const unsigned short* w3 = &Wl[(3*128 + h)*136];
    for(int k = 0; k < 128; k += 4){
      const float4 hv = *(const float4*)&hr[k];
      const ushort4 a0 = *(const ushort4*)&w0[k];
      const ushort4 a1 = *(const ushort4*)&w1[k];
      const ushort4 a2 = *(const ushort4*)&w2[k];
      const ushort4 a3 = *(const ushort4*)&w3[k];
      g0 += hv.x*bf2f(a0.x) + hv.y*bf2f(a0.y) + hv.z*bf2f(a0.z) + hv.w*bf2f(a0.w);
      g1 += hv.x*bf2f(a1.x) + hv.y*bf2f(a1.y) + hv.z*bf2f(a1.z) + hv.w*bf2f(a1.w);
      g2 += hv.x*bf2f(a2.x) + hv.y*bf2f(a2.y) + hv.z*bf2f(a2.z) + hv.w*bf2f(a2.w);
      g3 += hv.x*bf2f(a3.x) + hv.y*bf2f(a3.y) + hv.z*bf2f(a3.z) + hv.w*bf2f(a3.w);
    }
    const float iv = sigf(g0);
    const float fv = sigf(g1);
    const float gv = tanhf(g2);
    const float ov = sigf(g3);
    cc = fv*cc + iv*gv;
    const float hn = ov * tanhf(cc);
    __syncthreads();
    hS[b*128 + h] = hn;
    out[(t*8 + b)*1024 + n*128 + h] = hn;
    if(t == 15){
      out[131072 + (b*8 + n)*128 + h] = hn;
      out[139264 + (b*8 + n)*128 + h] = cc;
    }
    __syncthreads();
  }
}

// ---------------------------------------------------------------------------
// Tier-C fallback (round-2 verified, no extra ws): fused VALU gemm
// ---------------------------------------------------------------------------
__global__ __launch_bounds__(256) void k_gemm_old(
    const float* __restrict__ img, const float* __restrict__ gate,
    const float* __restrict__ cw, const float* __restrict__ cb,
    const float* __restrict__ sh, const float* __restrict__ tar,
    const float* __restrict__ Wih, const float* __restrict__ bih,
    const float* __restrict__ bhh, float* __restrict__ xg)
{
  __shared__ __align__(16) float imgS[16*545];
  __shared__ __align__(16) float WtS[16*132];
  __shared__ float PS[16*17];
  __shared__ float gateS[16*32];
  __shared__ float cw2S[16*32];
  __shared__ float cwS[32*32];
  __shared__ float cbS[32];
  __shared__ float shS[128];
  __shared__ float tarS[16*145];

  const int tid = threadIdx.x;
  const int g0  = blockIdx.x * 128;
  const int tb0 = blockIdx.y * 16;
  const int n   = blockIdx.z;
  const int gth = tid & 31;
  const int rth = tid >> 5;
  const long wbase = (long)(n*G4H + g0) * MEMIN;

  for(int i = tid; i < 16*32; i += 256){
    int r = i >> 5, c = i & 31;
    gateS[i] = gate[((tb0 + r)*N_ + n)*C_ + c];
  }
  for(int i = tid; i < 32*32; i += 256) cwS[i] = cw[i];
  if(tid < 32)  cbS[tid] = cb[tid];
  if(tid < 128) shS[tid] = sh[tid];
  for(int i = tid; i < 16*TAR_; i += 256)
    tarS[i] = tar[tb0*TAR_ + i];

  float acc0[4] = {0,0,0,0}, acc1[4] = {0,0,0,0};

  for(int s = 0; s < 16; ++s){
    __syncthreads();
    for(int i = tid; i < 8192; i += 256){
      int j = i & 15, c = (i >> 4) & 31, r = i >> 9;
      imgS[r*545 + c*17 + j] = img[((tb0 + r)*C_ + c)*HW_ + s*16 + j];
    }
    for(int d = 0; d < 32; ++d){
      __syncthreads();
      for(int i = tid; i < 2048; i += 256){
        int g = i >> 4, j = i & 15;
        WtS[j*132 + g] = Wih[wbase + (long)g*MEMIN + d*HW_ + s*16 + j];
      }
      for(int i = tid; i < 512; i += 256)
        cw2S[i] = gateS[i] * cwS[d*32 + (i & 31)];
      __syncthreads();
      {
        int j = tid & 15, r = tid >> 4;
        float a = cbS[d];
        const float* c2 = &cw2S[r*32];
        const float* im = &imgS[r*545 + j];
        #pragma unroll
        for(int c = 0; c < 32; ++c) a += c2[c] * im[c*17];
        PS[j*17 + r] = a;
      }
      __syncthreads();
      #pragma unroll
      for(int j = 0; j < 16; ++j){
        const float4 w = *(const float4*)&WtS[j*132 + (gth << 2)];
        const float p0 = PS[j*17 + (rth << 1)];
        const float p1 = PS[j*17 + (rth << 1) + 1];
        acc0[0] += p0*w.x; acc0[1] += p0*w.y; acc0[2] += p0*w.z; acc0[3] += p0*w.w;
        acc1[0] += p1*w.x; acc1[1] += p1*w.y; acc1[2] += p1*w.z; acc1[3] += p1*w.w;
      }
    }
  }
  {
    float ta[4] = {0,0,0,0};
    for(int kc = 0; kc < 8; ++kc){
      __syncthreads();
      for(int i = tid; i < 2048; i += 256){
        int g = i >> 4, j = i & 15;
        WtS[j*132 + g] = Wih[wbase + (long)g*MEMIN + 8192 + kc*16 + j];
      }
      __syncthreads();
      #pragma unroll
      for(int j = 0; j < 16; ++j){
        const float4 w = *(const float4*)&WtS[j*132 + (gth << 2)];
        const float sv = shS[kc*16 + j];
        ta[0] += sv*w.x; ta[1] += sv*w.y; ta[2] += sv*w.z; ta[3] += sv*w.w;
      }
    }
    acc0[0] += ta[0]; acc0[1] += ta[1]; acc0[2] += ta[2]; acc0[3] += ta[3];
    acc1[0] += ta[0]; acc1[1] += ta[1]; acc1[2] += ta[2]; acc1[3] += ta[3];
  }
  for(int kc = 0; kc < 10; ++kc){
    const int kendl = (kc == 9) ? 1 : 16;
    __syncthreads();
    for(int i = tid; i < 2048; i += 256){
      int g = i >> 4, j = i & 15;
      if(j < kendl)
        WtS[j*132 + g] = Wih[wbase + (long)g*MEMIN + 8320 + kc*16 + j];
    }
    __syncthreads();
    for(int j = 0; j < kendl; ++j){
      const float4 w = *(const float4*)&WtS[j*132 + (gth << 2)];
      const float p0 = tarS[(rth << 1)*TAR_ + kc*16 + j];
      const float p1 = tarS[((rth << 1) + 1)*TAR_ + kc*16 + j];
      acc0[0] += p0*w.x; acc0[1] += p0*w.y; acc0[2] += p0*w.z; acc0[3] += p0*w.w;
      acc1[0] += p1*w.x; acc1[1] += p1*w.y; acc1[2] += p1*w.z; acc1[3] += p1*w.w;
    }
  }
  {
    const int gg = g0 + (gth << 2);
    const float b0 = bih[n*G4H + gg + 0] + bhh[n*G4H + gg + 0];
    const float b1 = bih[n*G4H + gg + 1] + bhh[n*G4H + gg + 1];
    const float b2 = bih[n*G4H + gg + 2] + bhh[n*G4H + gg + 2];
    const float b3 = bih[n*G4H + gg + 3] + bhh[n*G4H + gg + 3];
    const int row = tb0 + (rth << 1);
    float4 o0 = make_float4(acc0[0]+b0, acc0[1]+b1, acc0[2]+b2, acc0[3]+b3);
    *(float4*)&xg[((long)(row*N_ + n))*G4H + gg] = o0;
    float4 o1 = make_float4(acc1[0]+b0, acc1[1]+b1, acc1[2]+b2, acc1[3]+b3);
    *(float4*)&xg[((long)((row + 1)*N_ + n))*G4H + gg] = o1;
  }
}

// ---------------------------------------------------------------------------
extern "C" void kernel_launch(void* const* d_in, const int* in_sizes, int n_in,
                              void* d_out, int out_size, void* d_ws, size_t ws_size,
                              hipStream_t stream)
{
  (void)in_sizes; (void)n_in; (void)out_size;
  const float* img  = (const float*)d_in[0];
  const float* tar  = (const float*)d_in[1];
  const float* WvB  = (const float*)d_in[7];
  const float* WoW  = (const float*)d_in[8];
  const float* WoB  = (const float*)d_in[9];
  const float* tdw  = (const float*)d_in[10];
  const float* tdb  = (const float*)d_in[11];
  const float* cw   = (const float*)d_in[12];
  const float* cb   = (const float*)d_in[13];
  const float* Wih  = (const float*)d_in[14];
  const float* Whh  = (const float*)d_in[15];
  const float* bih  = (const float*)d_in[16];
  const float* bhh  = (const float*)d_in[17];

  float* wsf   = (float*)d_ws;
  float* gatew = wsf;                       // 32768 f
  float* shw   = wsf + 32768;               // 128 f

  // Tier A layout: xg4 @ f32[32896..2130048) (4 x 524288), mem @ byte 8520192
  float* xg4w = wsf + 32896;
  unsigned short* memA = (unsigned short*)((char*)d_ws + 8520192);
  const size_t WS_A = 8520192 + (size_t)8*128*AK*2;          // 25,887,232 B

  // Tier B layout (round-3): xg @ f32[32896..557184), mem @ byte 2228736
  float* xgB = wsf + 32896;
  unsigned short* memB = (unsigned short*)((char*)d_ws + 2228736);
  const size_t WS_B = 2228736 + (size_t)8*128*AK*2;          // 19,595,776 B

  k_shared<<<128, 64, 0, stream>>>(WvB, WoW, WoB, shw);
  k_gate<<<dim3(8, 8), 256, 0, stream>>>(tar, tdw, tdb, gatew);

  if(ws_size >= WS_A){
    k_conv2<<<dim3(128, 8), 256, 0, stream>>>(img, gatew, cw, cb, shw, tar, memA);
    k_gemm4<<<dim3(16, 8, 4), 512, 0, stream>>>(memA, Wih, xg4w);
    k_lstm2<<<64, 512, 0, stream>>>(xg4w, Whh, bih, bhh, (float*)d_out);
  } else if(ws_size >= WS_B){
    k_conv<<<128, 512, 0, stream>>>(img, gatew, cw, cb, shw, tar, memB);
    k_bias<<<2048, 256, 0, stream>>>(bih, bhh, xgB);
    k_gemm_mfma<<<dim3(32, 8, 4), 256, 0, stream>>>(memB, Wih, xgB);
    (void)hipFuncSetAttribute((const void*)k_lstm,
                              hipFuncAttributeMaxDynamicSharedMemorySize, 143360);
    k_lstm<<<8, 1024, 143360, stream>>>(xgB, Whh, (float*)d_out);
  } else {
    k_gemm_old<<<dim3(4, 8, 8), 256, 0, stream>>>(img, gatew, cw, cb, shw, tar,
                                                  Wih, bih, bhh, xgB);
    (void)hipFuncSetAttribute((const void*)k_lstm,
                              hipFuncAttributeMaxDynamicSharedMemorySize, 143360);
    k_lstm<<<8, 1024, 143360, stream>>>(xgB, Whh, (float*)d_out);
  }
}

// Round 8
// 127.099 us; speedup vs baseline: 1.3007x; 1.2850x over previous
//
#include <hip/hip_runtime.h>

#define T_   16
#define B_   8
#define N_   8
#define H_   128
#define C_   32
#define HW_  256
#define TAR_ 145
#define G4H  512
#define MEMIN 8593
#define AK   8512   // padded K (multiple of 64): 8192 conv + 128 shared + 145 tar + 47 zero
#define XGN  524288 // elements per xg buffer
#define KSTEP 64

typedef __attribute__((ext_vector_type(8))) short short8v;
typedef __attribute__((ext_vector_type(4))) float f32x4;
typedef __attribute__((ext_vector_type(4), aligned(4))) float f32x4u; // 4B-aligned vec load

__device__ __forceinline__ float bf2f(unsigned short u){
  return __uint_as_float(((unsigned int)u) << 16);
}
__device__ __forceinline__ unsigned short f2bf(float x){
  unsigned int b = __float_as_uint(x);
  return (unsigned short)((b + 0x7fffu + ((b >> 16) & 1u)) >> 16);
}
// pack two f32 -> two bf16 (round-nearest-ties-away) in one dword via v_perm_b32
__device__ __forceinline__ unsigned pkbf(float lo, float hi){
  return __builtin_amdgcn_perm(__float_as_uint(hi) + 0x8000u,
                               __float_as_uint(lo) + 0x8000u, 0x07060302u);
}
__device__ __forceinline__ float bflo(unsigned w){ return __uint_as_float(w << 16); }
__device__ __forceinline__ float bfhi(unsigned w){ return __uint_as_float(w & 0xffff0000u); }
__device__ __forceinline__ float sigf(float x){ return 1.f/(1.f + expf(-x)); }

// async global->LDS DMA (HW adds lane*size to the wave-uniform LDS base)
__device__ __forceinline__ void gl_lds16(const void* g, void* l){
  __builtin_amdgcn_global_load_lds(
      (const __attribute__((address_space(1))) unsigned int*)g,
      (__attribute__((address_space(3))) unsigned int*)l, 16, 0, 0);
}
__device__ __forceinline__ void gl_lds4(const void* g, void* l){
  __builtin_amdgcn_global_load_lds(
      (const __attribute__((address_space(1))) unsigned int*)g,
      (__attribute__((address_space(3))) unsigned int*)l, 4, 0, 0);
}

// ---------------------------------------------------------------------------
// shared[h] = Wo_b[h] + sum_d Wv_b[d] * Wo_w[h,d]   (attention collapses)
// ---------------------------------------------------------------------------
__global__ void k_shared(const float* __restrict__ WvB, const float* __restrict__ WoW,
                         const float* __restrict__ WoB, float* __restrict__ sh){
  const int h = blockIdx.x, lane = threadIdx.x;
  float acc = 0.f;
  for(int d = lane; d < 896; d += 64) acc += WvB[d] * WoW[h*896 + d];
  for(int s = 32; s; s >>= 1) acc += __shfl_down(acc, s);
  if(lane == 0) sh[h] = acc + WoB[h];
}

// ---------------------------------------------------------------------------
// gate[tb,n,c] = sigmoid(td_b[n,c] + sum_{x<145} tar[tb,x]*td_w[n,c,x])
// ---------------------------------------------------------------------------
__global__ __launch_bounds__(256) void k_gate(const float* __restrict__ tar,
                                              const float* __restrict__ tdw,
                                              const float* __restrict__ tdb,
                                              float* __restrict__ gate){
  __shared__ float twS[32*145];
  __shared__ float taS[16*145];
  const int tb0 = blockIdx.x * 16, n = blockIdx.y, tid = threadIdx.x;
  for(int i = tid; i < 32*145; i += 256){
    int c = i / 145, x = i - c*145;
    twS[i] = tdw[(n*32 + c)*273 + x];
  }
  for(int i = tid; i < 16*145; i += 256)
    taS[i] = tar[tb0*145 + i];
  __syncthreads();
  for(int o = tid; o < 512; o += 256){
    int r = o >> 5, c = o & 31;
    float a = tdb[n*32 + c];
    const float* tr = &taS[r*145];
    const float* tw = &twS[c*145];
    for(int x = 0; x < 145; ++x) a += tr[x]*tw[x];
    gate[((tb0 + r)*N_ + n)*C_ + c] = 1.f/(1.f + expf(-a));
  }
}

// ---------------------------------------------------------------------------
// conv v2: grid (tb=128, n=8), 256 threads = hw.  Tail covers [8192..8512).
// ---------------------------------------------------------------------------
__global__ __launch_bounds__(256) void k_conv2(
    const float* __restrict__ img, const float* __restrict__ gate,
    const float* __restrict__ cw, const float* __restrict__ cb,
    const float* __restrict__ sh, const float* __restrict__ tar,
    unsigned short* __restrict__ mem)
{
  __shared__ float imgS[8192];    // [c][hw]
  __shared__ float cwgT[1024];    // [c][d] = cw[d][c]*gate[n][c]
  const int tb = blockIdx.x, n = blockIdx.y;
  const int hw = threadIdx.x;
  for(int i = hw; i < 8192; i += 256)
    imgS[i] = img[(size_t)tb*8192 + i];
  for(int i = hw; i < 1024; i += 256){
    const int c = i >> 5, d = i & 31;
    cwgT[i] = cw[d*32 + c] * gate[(tb*8 + n)*32 + c];
  }
  __syncthreads();
  f32x4 acc[8];
  #pragma unroll
  for(int dq = 0; dq < 8; ++dq){
    const f32x4u cv = *(const f32x4u*)&cb[dq*4];
    acc[dq].x = cv.x; acc[dq].y = cv.y; acc[dq].z = cv.z; acc[dq].w = cv.w;
  }
  #pragma unroll 4
  for(int c = 0; c < 32; ++c){
    const float iv = imgS[c*256 + hw];
    #pragma unroll
    for(int dq = 0; dq < 8; ++dq){
      const f32x4 w = *(const f32x4*)&cwgT[c*32 + dq*4];
      acc[dq].x += iv*w.x; acc[dq].y += iv*w.y;
      acc[dq].z += iv*w.z; acc[dq].w += iv*w.w;
    }
  }
  unsigned short* mrow = mem + (size_t)(n*128 + tb)*AK;
  #pragma unroll
  for(int dq = 0; dq < 8; ++dq){
    mrow[(dq*4 + 0)*256 + hw] = f2bf(acc[dq].x);
    mrow[(dq*4 + 1)*256 + hw] = f2bf(acc[dq].y);
    mrow[(dq*4 + 2)*256 + hw] = f2bf(acc[dq].z);
    mrow[(dq*4 + 3)*256 + hw] = f2bf(acc[dq].w);
  }
  for(int i = hw; i < 320; i += 256){
    if(i < 128)      mrow[8192 + i]       = f2bf(sh[i]);
    else if(i < 273) mrow[8320 + i - 128] = f2bf(tar[tb*TAR_ + i - 128]);
    else             mrow[8465 + i - 273] = 0;   // zeros to 8512
  }
}

// ---------------------------------------------------------------------------
// MFMA GEMM v5 (m97-pattern): grid (32 gt, 8 n, 4 ks), 256 thr / 4 waves.
// Tile 128r x 16g, K-step 64, DOUBLE-BUFFERED LDS filled by global_load_lds
// (async DMA, compiler cannot sink it).  A: bf16, linear LDS + pre-swizzled
// global source (chunk ^= row&7) -> conflict-free ds_read_b128.  B: f32 rows
// only 4B-aligned -> dword DMA, 32B-block swizzle (jb ^= g&7).  One
// __syncthreads per step (drains DMA; the documented ~20% stall).
// C/D: col=lane&15, row=(lane>>4)*4+j  (HW-verified layout).
// ---------------------------------------------------------------------------
__global__ __launch_bounds__(256) void k_gemm5(
    const unsigned short* __restrict__ mem, const float* __restrict__ Wih,
    float* __restrict__ xg4)
{
  __shared__ unsigned short Abuf[2][128*64];   // 16 KB each: [row][64k] linear
  __shared__ float          Bbuf[2][16*64];    //  4 KB each: [g][64k f32]
  const int gt = blockIdx.x, n = blockIdx.y, ks = blockIdx.z;
  const int tid = threadIdx.x;
  const int wv = tid >> 6, ln = tid & 63;
  const int lr = ln & 15, lg = ln >> 4;
  const int g0 = gt*16;
  const int kbeg = (ks == 0) ? 0 : 2176 + (ks - 1)*2112;
  const int nsteps = (ks == 0) ? 34 : 33;     // 34+33*3 = 133 steps * 64 = 8512
  const unsigned short* An = mem + (size_t)n*128*AK;
  const float* Bn = Wih + (size_t)(n*G4H + g0)*MEMIN;

#define STAGE5(bb, kk) do{                                                     \
    _Pragma("unroll")                                                          \
    for(int i_ = 0; i_ < 4; ++i_){                                             \
      const int ci_ = i_*256 + tid;                                            \
      const int row_ = ci_ >> 3;                                               \
      const unsigned short* src_ = An + (size_t)row_*AK + (kk)                 \
                                   + (((ci_ & 7) ^ (row_ & 7)) << 3);          \
      gl_lds16(src_, &Abuf[bb][(i_*256 + wv*64)*8]);                           \
    }                                                                          \
    _Pragma("unroll")                                                          \
    for(int q_ = 0; q_ < 4; ++q_){                                             \
      const int idx_ = q_*256 + tid;                                           \
      const int g_ = idx_ >> 6;                                                \
      const int kd_ = idx_ & 63;                                               \
      const float* srcB_ = Bn + (size_t)g_*MEMIN + (kk)                        \
                           + ((((kd_ >> 3) ^ (g_ & 7)) << 3) + (kd_ & 7));     \
      gl_lds4(srcB_, &Bbuf[bb][q_*256 + wv*64]);                               \
    }                                                                          \
  }while(0)

  f32x4 acc0 = {0.f,0.f,0.f,0.f};
  f32x4 acc1 = {0.f,0.f,0.f,0.f};

  STAGE5(0, kbeg);
  __syncthreads();

  int b = 0;
  for(int t = 0; t < nsteps; ++t){
    if(t + 1 < nsteps) STAGE5(b^1, kbeg + (t+1)*KSTEP);
    #pragma unroll
    for(int s = 0; s < 2; ++s){
      const int jb = (s*4 + lg) ^ (lr & 7);
      const float* bp = &Bbuf[b][lr*64 + jb*8];
      const f32x4 blo = *(const f32x4*)bp;
      const f32x4 bhi = *(const f32x4*)(bp + 4);
      short8v bf;
      unsigned* u = (unsigned*)&bf;
      u[0] = pkbf(blo.x, blo.y); u[1] = pkbf(blo.z, blo.w);
      u[2] = pkbf(bhi.x, bhi.y); u[3] = pkbf(bhi.z, bhi.w);
      const short8v a0 = *(const short8v*)&Abuf[b][(wv*32 + lr)*64 + jb*8];
      const short8v a1 = *(const short8v*)&Abuf[b][(wv*32 + 16 + lr)*64 + jb*8];
      acc0 = __builtin_amdgcn_mfma_f32_16x16x32_bf16(a0, bf, acc0, 0, 0, 0);
      acc1 = __builtin_amdgcn_mfma_f32_16x16x32_bf16(a1, bf, acc1, 0, 0, 0);
    }
    __syncthreads();
    b ^= 1;
  }
#undef STAGE5

  float* dst = xg4 + (size_t)ks*XGN;
  const int c0 = g0 + lr;
  const int r0 = wv*32 + lg*4, r1 = r0 + 16;
  #pragma unroll
  for(int j = 0; j < 4; ++j){
    dst[(size_t)((r0 + j)*8 + n)*G4H + c0] = acc0[j];
    dst[(size_t)((r1 + j)*8 + n)*G4H + c0] = acc1[j];
  }
}

// ---------------------------------------------------------------------------
// LSTM v2: 64 blocks = (b,n) pairs, 512 threads = gate-row g.  Whh row held
// packed-bf16 in 64 VGPRs (loaded once).  Per step: sum 4 K-split xg buffers
// + bias, dot over broadcast h (LDS), activations by threads<128.
// ---------------------------------------------------------------------------
__global__ __launch_bounds__(512) void k_lstm2(
    const float* __restrict__ xg4, const float* __restrict__ Whh,
    const float* __restrict__ bih, const float* __restrict__ bhh,
    float* __restrict__ out)
{
  __shared__ float hS[128];
  __shared__ float preS[512];
  const int bn = blockIdx.x;
  const int n = bn & 7, b = bn >> 3;
  const int g = threadIdx.x;

  unsigned wr[64];
  const float* wrow = Whh + (size_t)(n*G4H + g)*H_;
  #pragma unroll
  for(int i = 0; i < 32; ++i){
    const f32x4 w = *(const f32x4*)(wrow + i*4);
    wr[2*i]   = pkbf(w.x, w.y);
    wr[2*i+1] = pkbf(w.z, w.w);
  }
  const float bias = bih[n*G4H + g] + bhh[n*G4H + g];
  if(g < 128) hS[g] = 0.f;
  float cc = 0.f;
  __syncthreads();

  for(int t = 0; t < 16; ++t){
    const size_t xb = (size_t)((t*8 + b)*8 + n)*G4H + g;
    float acc = bias + xg4[xb] + xg4[xb + XGN] + xg4[xb + 2*XGN] + xg4[xb + 3*XGN];
    #pragma unroll
    for(int q = 0; q < 32; ++q){
      const f32x4 hv = *(const f32x4*)&hS[q*4];
      const unsigned w0 = wr[2*q], w1 = wr[2*q+1];
      acc += hv.x*bflo(w0) + hv.y*bfhi(w0) + hv.z*bflo(w1) + hv.w*bfhi(w1);
    }
    preS[g] = acc;
    __syncthreads();
    if(g < 128){
      const float iv = sigf(preS[g]);
      const float fv = sigf(preS[128 + g]);
      const float gv = tanhf(preS[256 + g]);
      const float ov = sigf(preS[384 + g]);
      cc = fv*cc + iv*gv;
      const float hn = ov*tanhf(cc);
      hS[g] = hn;
      out[(t*8 + b)*1024 + n*128 + g] = hn;
      if(t == 15){
        out[131072 + (b*8 + n)*128 + g] = hn;   // hT
        out[139264 + (b*8 + n)*128 + g] = cc;   // cT
      }
    }
    __syncthreads();
  }
}

// ---------------------------------------------------------------------------
// Tier-B fallbacks (round-3 verified): conv v1 + bias init + atomic MFMA gemm
// + old lstm
// ---------------------------------------------------------------------------
__global__ __launch_bounds__(512) void k_conv(
    const float* __restrict__ img, const float* __restrict__ gate,
    const float* __restrict__ cw, const float* __restrict__ cb,
    const float* __restrict__ sh, const float* __restrict__ tar,
    unsigned short* __restrict__ mem)
{
  __shared__ float imgS[8192];
  __shared__ float cwgS[1024];
  __shared__ float shS[128];
  __shared__ float tarS[160];
  const int tb = blockIdx.x, tid = threadIdx.x;
  for(int i = tid; i < 8192; i += 512)
    imgS[i] = img[(size_t)tb*8192 + i];
  if(tid < 128) shS[tid] = sh[tid];
  if(tid >= 128 && tid < 273) tarS[tid-128] = tar[tb*TAR_ + tid - 128];
  for(int n = 0; n < 8; ++n){
    __syncthreads();
    for(int i = tid; i < 1024; i += 512)
      cwgS[i] = cw[i] * gate[(tb*8 + n)*32 + (i & 31)];
    __syncthreads();
    unsigned short* mrow = mem + (size_t)(n*128 + tb)*AK;
    for(int q = 0; q < 4; ++q){
      const int idx = q*2048 + tid*4;
      const int d = idx >> 8, hw = idx & 255;
      const float bias = cb[d];
      float a0 = bias, a1 = bias, a2 = bias, a3 = bias;
      const float* cg = &cwgS[d*32];
      #pragma unroll
      for(int c = 0; c < 32; ++c){
        const f32x4 iv = *(const f32x4*)&imgS[c*256 + hw];
        const float w = cg[c];
        a0 += w*iv.x; a1 += w*iv.y; a2 += w*iv.z; a3 += w*iv.w;
      }
      ushort4 o;
      o.x = f2bf(a0); o.y = f2bf(a1); o.z = f2bf(a2); o.w = f2bf(a3);
      *(ushort4*)&mrow[idx] = o;
    }
    if(tid < 128)      mrow[8192 + tid]       = f2bf(shS[tid]);
    else if(tid < 273) mrow[8320 + tid - 128] = f2bf(tarS[tid - 128]);
    else if(tid < 320) mrow[8465 + tid - 273] = 0;   // zeros to 8512
  }
}

__global__ __launch_bounds__(256) void k_bias(const float* __restrict__ bih,
                                              const float* __restrict__ bhh,
                                              float* __restrict__ xg){
  const int i = blockIdx.x*256 + threadIdx.x;
  const int ng = ((i >> 9) & 7)*512 + (i & 511);
  xg[i] = bih[ng] + bhh[ng];
}

__global__ __launch_bounds__(256) void k_gemm_mfma(
    const unsigned short* __restrict__ mem, const float* __restrict__ Wih,
    float* __restrict__ xg)
{
  const int gt = blockIdx.x, n = blockIdx.y, ks = blockIdx.z;
  const int wv = threadIdx.x >> 6, ln = threadIdx.x & 63;
  const int lr = ln & 15, lg = ln >> 4;
  const int g0 = gt*16;
  const int kbeg = (ks==0) ? 0 : (ks==1) ? 2144 : (ks==2) ? 4256 : 6368;
  const int kend = (ks==0) ? 2144 : (ks==1) ? 4256 : (ks==2) ? 6368 : 8480;
  const float* Bp = Wih + (size_t)(n*G4H + g0 + lr)*MEMIN + lg*8;
  const unsigned short* Ap = mem + (size_t)(n*128 + wv*32 + lr)*AK + lg*8;
  f32x4 acc0 = {0.f,0.f,0.f,0.f};
  f32x4 acc1 = {0.f,0.f,0.f,0.f};
  #pragma unroll 2
  for(int k = kbeg; k < kend; k += 32){
    const f32x4u blo = *(const f32x4u*)(Bp + k);
    const f32x4u bhi = *(const f32x4u*)(Bp + k + 4);
    short8v bf;
    unsigned* bu = (unsigned*)&bf;
    bu[0] = pkbf(blo.x, blo.y); bu[1] = pkbf(blo.z, blo.w);
    bu[2] = pkbf(bhi.x, bhi.y); bu[3] = pkbf(bhi.z, bhi.w);
    const short8v a0 = *(const short8v*)(Ap + k);
    const short8v a1 = *(const short8v*)(Ap + (size_t)16*AK + k);
    acc0 = __builtin_amdgcn_mfma_f32_16x16x32_bf16(a0, bf, acc0, 0, 0, 0);
    acc1 = __builtin_amdgcn_mfma_f32_16x16x32_bf16(a1, bf, acc1, 0, 0, 0);
  }
  const int col = g0 + lr;
  const int r0  = wv*32 + lg*4;
  #pragma unroll
  for(int j = 0; j < 4; ++j){
    atomicAdd(&xg[(size_t)((r0 + j)*8 + n)*G4H + col],      acc0[j]);
    atomicAdd(&xg[(size_t)((r0 + 16 + j)*8 + n)*G4H + col], acc1[j]);
  }
}

__global__ __launch_bounds__(1024) void k_lstm(
    const float* __restrict__ xg, const float* __restrict__ Whh,
    float* __restrict__ out)
{
  extern __shared__ char smem[];
  unsigned short* Wl = (unsigned short*)smem;
  float* hS = (float*)(smem + 512*136*sizeof(unsigned short));

  const int n = blockIdx.x, tid = threadIdx.x;
  for(int i = tid; i < 512*128; i += 1024){
    int g = i >> 7, k = i & 127;
    Wl[g*136 + k] = f2bf(Whh[n*512*128 + i]);
  }
  hS[tid] = 0.f;
  const int h = tid >> 3, b = tid & 7;
  float cc = 0.f;
  __syncthreads();

  for(int t = 0; t < 16; ++t){
    const long xbase = ((long)((t*8 + b)*8 + n))*G4H + h;
    float g0 = xg[xbase + 0*128];
    float g1 = xg[xbase + 1*128];
    float g2 = xg[xbase + 2*128];
    float g3 = xg[xbase + 3*128];
    const float* hr = &hS[b*128];
    const unsigned short* w0 = &Wl[(0*128 + h)*136];
    const unsigned short* w1 = &Wl[(1*128 + h)*136];
    const unsigned short* w2 = &Wl[(2*128 + h)*136];
    const unsigned short* w3 = &Wl[(3*128 + h)*136];
    for(int k = 0; k < 128; k += 4){
      const float4 hv = *(const float4*)&hr[k];
      const ushort4 a0 = *(const ushort4*)&w0[k];
      const ushort4 a1 = *(const ushort4*)&w1[k];
      const ushort4 a2 = *(const ushort4*)&w2[k];
      const ushort4 a3 = *(const ushort4*)&w3[k];
      g0 += hv.x*bf2f(a0.x) + hv.y*bf2f(a0.y) + hv.z*bf2f(a0.z) + hv.w*bf2f(a0.w);
      g1 += hv.x*bf2f(a1.x) + hv.y*bf2f(a1.y) + hv.z*bf2f(a1.z) + hv.w*bf2f(a1.w);
      g2 += hv.x*bf2f(a2.x) + hv.y*bf2f(a2.y) + hv.z*bf2f(a2.z) + hv.w*bf2f(a2.w);
      g3 += hv.x*bf2f(a3.x) + hv.y*bf2f(a3.y) + hv.z*bf2f(a3.z) + hv.w*bf2f(a3.w);
    }
    const float iv = sigf(g0);
    const float fv = sigf(g1);
    const float gv = tanhf(g2);
    const float ov = sigf(g3);
    cc = fv*cc + iv*gv;
    const float hn = ov * tanhf(cc);
    __syncthreads();
    hS[b*128 + h] = hn;
    out[(t*8 + b)*1024 + n*128 + h] = hn;
    if(t == 15){
      out[131072 + (b*8 + n)*128 + h] = hn;
      out[139264 + (b*8 + n)*128 + h] = cc;
    }
    __syncthreads();
  }
}

// ---------------------------------------------------------------------------
// Tier-C fallback (round-2 verified, no extra ws): fused VALU gemm
// ---------------------------------------------------------------------------
__global__ __launch_bounds__(256) void k_gemm_old(
    const float* __restrict__ img, const float* __restrict__ gate,
    const float* __restrict__ cw, const float* __restrict__ cb,
    const float* __restrict__ sh, const float* __restrict__ tar,
    const float* __restrict__ Wih, const float* __restrict__ bih,
    const float* __restrict__ bhh, float* __restrict__ xg)
{
  __shared__ __align__(16) float imgS[16*545];
  __shared__ __align__(16) float WtS[16*132];
  __shared__ float PS[16*17];
  __shared__ float gateS[16*32];
  __shared__ float cw2S[16*32];
  __shared__ float cwS[32*32];
  __shared__ float cbS[32];
  __shared__ float shS[128];
  __shared__ float tarS[16*145];

  const int tid = threadIdx.x;
  const int g0  = blockIdx.x * 128;
  const int tb0 = blockIdx.y * 16;
  const int n   = blockIdx.z;
  const int gth = tid & 31;
  const int rth = tid >> 5;
  const long wbase = (long)(n*G4H + g0) * MEMIN;

  for(int i = tid; i < 16*32; i += 256){
    int r = i >> 5, c = i & 31;
    gateS[i] = gate[((tb0 + r)*N_ + n)*C_ + c];
  }
  for(int i = tid; i < 32*32; i += 256) cwS[i] = cw[i];
  if(tid < 32)  cbS[tid] = cb[tid];
  if(tid < 128) shS[tid] = sh[tid];
  for(int i = tid; i < 16*TAR_; i += 256)
    tarS[i] = tar[tb0*TAR_ + i];

  float acc0[4] = {0,0,0,0}, acc1[4] = {0,0,0,0};

  for(int s = 0; s < 16; ++s){
    __syncthreads();
    for(int i = tid; i < 8192; i += 256){
      int j = i & 15, c = (i >> 4) & 31, r = i >> 9;
      imgS[r*545 + c*17 + j] = img[((tb0 + r)*C_ + c)*HW_ + s*16 + j];
    }
    for(int d = 0; d < 32; ++d){
      __syncthreads();
      for(int i = tid; i < 2048; i += 256){
        int g = i >> 4, j = i & 15;
        WtS[j*132 + g] = Wih[wbase + (long)g*MEMIN + d*HW_ + s*16 + j];
      }
      for(int i = tid; i < 512; i += 256)
        cw2S[i] = gateS[i] * cwS[d*32 + (i & 31)];
      __syncthreads();
      {
        int j = tid & 15, r = tid >> 4;
        float a = cbS[d];
        const float* c2 = &cw2S[r*32];
        const float* im = &imgS[r*545 + j];
        #pragma unroll
        for(int c = 0; c < 32; ++c) a += c2[c] * im[c*17];
        PS[j*17 + r] = a;
      }
      __syncthreads();
      #pragma unroll
      for(int j = 0; j < 16; ++j){
        const float4 w = *(const float4*)&WtS[j*132 + (gth << 2)];
        const float p0 = PS[j*17 + (rth << 1)];
        const float p1 = PS[j*17 + (rth << 1) + 1];
        acc0[0] += p0*w.x; acc0[1] += p0*w.y; acc0[2] += p0*w.z; acc0[3] += p0*w.w;
        acc1[0] += p1*w.x; acc1[1] += p1*w.y; acc1[2] += p1*w.z; acc1[3] += p1*w.w;
      }
    }
  }
  {
    float ta[4] = {0,0,0,0};
    for(int kc = 0; kc < 8; ++kc){
      __syncthreads();
      for(int i = tid; i < 2048; i += 256){
        int g = i >> 4, j = i & 15;
        WtS[j*132 + g] = Wih[wbase + (long)g*MEMIN + 8192 + kc*16 + j];
      }
      __syncthreads();
      #pragma unroll
      for(int j = 0; j < 16; ++j){
        const float4 w = *(const float4*)&WtS[j*132 + (gth << 2)];
        const float sv = shS[kc*16 + j];
        ta[0] += sv*w.x; ta[1] += sv*w.y; ta[2] += sv*w.z; ta[3] += sv*w.w;
      }
    }
    acc0[0] += ta[0]; acc0[1] += ta[1]; acc0[2] += ta[2]; acc0[3] += ta[3];
    acc1[0] += ta[0]; acc1[1] += ta[1]; acc1[2] += ta[2]; acc1[3] += ta[3];
  }
  for(int kc = 0; kc < 10; ++kc){
    const int kendl = (kc == 9) ? 1 : 16;
    __syncthreads();
    for(int i = tid; i < 2048; i += 256){
      int g = i >> 4, j = i & 15;
      if(j < kendl)
        WtS[j*132 + g] = Wih[wbase + (long)g*MEMIN + 8320 + kc*16 + j];
    }
    __syncthreads();
    for(int j = 0; j < kendl; ++j){
      const float4 w = *(const float4*)&WtS[j*132 + (gth << 2)];
      const float p0 = tarS[(rth << 1)*TAR_ + kc*16 + j];
      const float p1 = tarS[((rth << 1) + 1)*TAR_ + kc*16 + j];
      acc0[0] += p0*w.x; acc0[1] += p0*w.y; acc0[2] += p0*w.z; acc0[3] += p0*w.w;
      acc1[0] += p1*w.x; acc1[1] += p1*w.y; acc1[2] += p1*w.z; acc1[3] += p1*w.w;
    }
  }
  {
    const int gg = g0 + (gth << 2);
    const float b0 = bih[n*G4H + gg + 0] + bhh[n*G4H + gg + 0];
    const float b1 = bih[n*G4H + gg + 1] + bhh[n*G4H + gg + 1];
    const float b2 = bih[n*G4H + gg + 2] + bhh[n*G4H + gg + 2];
    const float b3 = bih[n*G4H + gg + 3] + bhh[n*G4H + gg + 3];
    const int row = tb0 + (rth << 1);
    float4 o0 = make_float4(acc0[0]+b0, acc0[1]+b1, acc0[2]+b2, acc0[3]+b3);
    *(float4*)&xg[((long)(row*N_ + n))*G4H + gg] = o0;
    float4 o1 = make_float4(acc1[0]+b0, acc1[1]+b1, acc1[2]+b2, acc1[3]+b3);
    *(float4*)&xg[((long)((row + 1)*N_ + n))*G4H + gg] = o1;
  }
}

// ---------------------------------------------------------------------------
extern "C" void kernel_launch(void* const* d_in, const int* in_sizes, int n_in,
                              void* d_out, int out_size, void* d_ws, size_t ws_size,
                              hipStream_t stream)
{
  (void)in_sizes; (void)n_in; (void)out_size;
  const float* img  = (const float*)d_in[0];
  const float* tar  = (const float*)d_in[1];
  const float* WvB  = (const float*)d_in[7];
  const float* WoW  = (const float*)d_in[8];
  const float* WoB  = (const float*)d_in[9];
  const float* tdw  = (const float*)d_in[10];
  const float* tdb  = (const float*)d_in[11];
  const float* cw   = (const float*)d_in[12];
  const float* cb   = (const float*)d_in[13];
  const float* Wih  = (const float*)d_in[14];
  const float* Whh  = (const float*)d_in[15];
  const float* bih  = (const float*)d_in[16];
  const float* bhh  = (const float*)d_in[17];

  float* wsf   = (float*)d_ws;
  float* gatew = wsf;                       // 32768 f
  float* shw   = wsf + 32768;               // 128 f

  // Tier A layout: xg4 @ f32[32896..2130048) (4 x 524288), mem @ byte 8520192
  float* xg4w = wsf + 32896;
  unsigned short* memA = (unsigned short*)((char*)d_ws + 8520192);
  const size_t WS_A = 8520192 + (size_t)8*128*AK*2;          // 25,952,768 B

  // Tier B layout (round-3): xg @ f32[32896..557184), mem @ byte 2228736
  float* xgB = wsf + 32896;
  unsigned short* memB = (unsigned short*)((char*)d_ws + 2228736);
  const size_t WS_B = 2228736 + (size_t)8*128*AK*2;          // 19,661,312 B

  k_shared<<<128, 64, 0, stream>>>(WvB, WoW, WoB, shw);
  k_gate<<<dim3(8, 8), 256, 0, stream>>>(tar, tdw, tdb, gatew);

  if(ws_size >= WS_A){
    k_conv2<<<dim3(128, 8), 256, 0, stream>>>(img, gatew, cw, cb, shw, tar, memA);
    k_gemm5<<<dim3(32, 8, 4), 256, 0, stream>>>(memA, Wih, xg4w);
    k_lstm2<<<64, 512, 0, stream>>>(xg4w, Whh, bih, bhh, (float*)d_out);
  } else if(ws_size >= WS_B){
    k_conv<<<128, 512, 0, stream>>>(img, gatew, cw, cb, shw, tar, memB);
    k_bias<<<2048, 256, 0, stream>>>(bih, bhh, xgB);
    k_gemm_mfma<<<dim3(32, 8, 4), 256, 0, stream>>>(memB, Wih, xgB);
    (void)hipFuncSetAttribute((const void*)k_lstm,
                              hipFuncAttributeMaxDynamicSharedMemorySize, 143360);
    k_lstm<<<8, 1024, 143360, stream>>>(xgB, Whh, (float*)d_out);
  } else {
    k_gemm_old<<<dim3(4, 8, 8), 256, 0, stream>>>(img, gatew, cw, cb, shw, tar,
                                                  Wih, bih, bhh, xgB);
    (void)hipFuncSetAttribute((const void*)k_lstm,
                              hipFuncAttributeMaxDynamicSharedMemorySize, 143360);
    k_lstm<<<8, 1024, 143360, stream>>>(xgB, Whh, (float*)d_out);
  }
}

// Round 9
// 123.744 us; speedup vs baseline: 1.3360x; 1.0271x over previous
//
#include <hip/hip_runtime.h>

#define T_   16
#define B_   8
#define N_   8
#define H_   128
#define C_   32
#define HW_  256
#define TAR_ 145
#define G4H  512
#define MEMIN 8593
#define AK   8512   // padded K (multiple of 64): 8192 conv + 128 shared + 145 tar + 47 zero
#define XGN  524288 // elements per xg buffer
#define KSTEP 64

typedef __attribute__((ext_vector_type(8))) short short8v;
typedef __attribute__((ext_vector_type(4))) float f32x4;
typedef __attribute__((ext_vector_type(4), aligned(4))) float f32x4u; // 4B-aligned vec load

__device__ __forceinline__ float bf2f(unsigned short u){
  return __uint_as_float(((unsigned int)u) << 16);
}
__device__ __forceinline__ unsigned short f2bf(float x){
  unsigned int b = __float_as_uint(x);
  return (unsigned short)((b + 0x7fffu + ((b >> 16) & 1u)) >> 16);
}
// pack two f32 -> two bf16 (round-nearest-ties-away) in one dword via v_perm_b32
__device__ __forceinline__ unsigned pkbf(float lo, float hi){
  return __builtin_amdgcn_perm(__float_as_uint(hi) + 0x8000u,
                               __float_as_uint(lo) + 0x8000u, 0x07060302u);
}
__device__ __forceinline__ float bflo(unsigned w){ return __uint_as_float(w << 16); }
__device__ __forceinline__ float bfhi(unsigned w){ return __uint_as_float(w & 0xffff0000u); }
__device__ __forceinline__ float sigf(float x){ return 1.f/(1.f + expf(-x)); }

// async global->LDS DMA (HW adds lane*size to the wave-uniform LDS base)
__device__ __forceinline__ void gl_lds16(const void* g, void* l){
  __builtin_amdgcn_global_load_lds(
      (const __attribute__((address_space(1))) unsigned int*)g,
      (__attribute__((address_space(3))) unsigned int*)l, 16, 0, 0);
}
__device__ __forceinline__ void gl_lds4(const void* g, void* l){
  __builtin_amdgcn_global_load_lds(
      (const __attribute__((address_space(1))) unsigned int*)g,
      (__attribute__((address_space(3))) unsigned int*)l, 4, 0, 0);
}

// ---------------------------------------------------------------------------
// shared[h] = Wo_b[h] + sum_d Wv_b[d] * Wo_w[h,d]   (attention collapses)
// ---------------------------------------------------------------------------
__global__ void k_shared(const float* __restrict__ WvB, const float* __restrict__ WoW,
                         const float* __restrict__ WoB, float* __restrict__ sh){
  const int h = blockIdx.x, lane = threadIdx.x;
  float acc = 0.f;
  for(int d = lane; d < 896; d += 64) acc += WvB[d] * WoW[h*896 + d];
  for(int s = 32; s; s >>= 1) acc += __shfl_down(acc, s);
  if(lane == 0) sh[h] = acc + WoB[h];
}

// ---------------------------------------------------------------------------
// gate[tb,n,c] = sigmoid(td_b[n,c] + sum_{x<145} tar[tb,x]*td_w[n,c,x])
// ---------------------------------------------------------------------------
__global__ __launch_bounds__(256) void k_gate(const float* __restrict__ tar,
                                              const float* __restrict__ tdw,
                                              const float* __restrict__ tdb,
                                              float* __restrict__ gate){
  __shared__ float twS[32*145];
  __shared__ float taS[16*145];
  const int tb0 = blockIdx.x * 16, n = blockIdx.y, tid = threadIdx.x;
  for(int i = tid; i < 32*145; i += 256){
    int c = i / 145, x = i - c*145;
    twS[i] = tdw[(n*32 + c)*273 + x];
  }
  for(int i = tid; i < 16*145; i += 256)
    taS[i] = tar[tb0*145 + i];
  __syncthreads();
  for(int o = tid; o < 512; o += 256){
    int r = o >> 5, c = o & 31;
    float a = tdb[n*32 + c];
    const float* tr = &taS[r*145];
    const float* tw = &twS[c*145];
    for(int x = 0; x < 145; ++x) a += tr[x]*tw[x];
    gate[((tb0 + r)*N_ + n)*C_ + c] = 1.f/(1.f + expf(-a));
  }
}

// ---------------------------------------------------------------------------
// conv v2: grid (tb=128, n=8), 256 threads = hw.  Tail covers [8192..8512).
// ---------------------------------------------------------------------------
__global__ __launch_bounds__(256) void k_conv2(
    const float* __restrict__ img, const float* __restrict__ gate,
    const float* __restrict__ cw, const float* __restrict__ cb,
    const float* __restrict__ sh, const float* __restrict__ tar,
    unsigned short* __restrict__ mem)
{
  __shared__ float imgS[8192];    // [c][hw]
  __shared__ float cwgT[1024];    // [c][d] = cw[d][c]*gate[n][c]
  const int tb = blockIdx.x, n = blockIdx.y;
  const int hw = threadIdx.x;
  for(int i = hw; i < 8192; i += 256)
    imgS[i] = img[(size_t)tb*8192 + i];
  for(int i = hw; i < 1024; i += 256){
    const int c = i >> 5, d = i & 31;
    cwgT[i] = cw[d*32 + c] * gate[(tb*8 + n)*32 + c];
  }
  __syncthreads();
  f32x4 acc[8];
  #pragma unroll
  for(int dq = 0; dq < 8; ++dq){
    const f32x4u cv = *(const f32x4u*)&cb[dq*4];
    acc[dq].x = cv.x; acc[dq].y = cv.y; acc[dq].z = cv.z; acc[dq].w = cv.w;
  }
  #pragma unroll 4
  for(int c = 0; c < 32; ++c){
    const float iv = imgS[c*256 + hw];
    #pragma unroll
    for(int dq = 0; dq < 8; ++dq){
      const f32x4 w = *(const f32x4*)&cwgT[c*32 + dq*4];
      acc[dq].x += iv*w.x; acc[dq].y += iv*w.y;
      acc[dq].z += iv*w.z; acc[dq].w += iv*w.w;
    }
  }
  unsigned short* mrow = mem + (size_t)(n*128 + tb)*AK;
  #pragma unroll
  for(int dq = 0; dq < 8; ++dq){
    mrow[(dq*4 + 0)*256 + hw] = f2bf(acc[dq].x);
    mrow[(dq*4 + 1)*256 + hw] = f2bf(acc[dq].y);
    mrow[(dq*4 + 2)*256 + hw] = f2bf(acc[dq].z);
    mrow[(dq*4 + 3)*256 + hw] = f2bf(acc[dq].w);
  }
  for(int i = hw; i < 320; i += 256){
    if(i < 128)      mrow[8192 + i]       = f2bf(sh[i]);
    else if(i < 273) mrow[8320 + i - 128] = f2bf(tar[tb*TAR_ + i - 128]);
    else             mrow[8465 + i - 273] = 0;   // zeros to 8512
  }
}

// ---------------------------------------------------------------------------
// MFMA GEMM v5b: round-8 structure + COUNTED vmcnt pipeline (T4).
// grid (32 gt, 8 n, 4 ks), 256 thr / 4 waves, tile 128r x 16g, K-step 64,
// double-buffered LDS via global_load_lds.  Per step:
//   s_waitcnt vmcnt(8)   <- stage(t) done, stage(t+1)'s 8 ops stay IN FLIGHT
//   s_barrier ; compute(buf b) ; s_barrier ; STAGE(buf b, t+2)
// (replaces __syncthreads whose vmcnt(0) drain collapsed the pipeline).
// C/D: col=lane&15, row=(lane>>4)*4+j  (HW-verified layout).
// ---------------------------------------------------------------------------
__global__ __launch_bounds__(256) void k_gemm5(
    const unsigned short* __restrict__ mem, const float* __restrict__ Wih,
    float* __restrict__ xg4)
{
  __shared__ unsigned short Abuf[2][128*64];   // 16 KB each: [row][64k] linear
  __shared__ float          Bbuf[2][16*64];    //  4 KB each: [g][64k f32]
  const int gt = blockIdx.x, n = blockIdx.y, ks = blockIdx.z;
  const int tid = threadIdx.x;
  const int wv = tid >> 6, ln = tid & 63;
  const int lr = ln & 15, lg = ln >> 4;
  const int g0 = gt*16;
  const int kbeg = (ks == 0) ? 0 : 2176 + (ks - 1)*2112;
  const int nsteps = (ks == 0) ? 34 : 33;     // 34+33*3 = 133 steps * 64 = 8512
  const unsigned short* An = mem + (size_t)n*128*AK;
  const float* Bn = Wih + (size_t)(n*G4H + g0)*MEMIN;

#define STAGE5(bb, kk) do{                                                     \
    _Pragma("unroll")                                                          \
    for(int i_ = 0; i_ < 4; ++i_){                                             \
      const int ci_ = i_*256 + tid;                                            \
      const int row_ = ci_ >> 3;                                               \
      const unsigned short* src_ = An + (size_t)row_*AK + (kk)                 \
                                   + (((ci_ & 7) ^ (row_ & 7)) << 3);          \
      gl_lds16(src_, &Abuf[bb][(i_*256 + wv*64)*8]);                           \
    }                                                                          \
    _Pragma("unroll")                                                          \
    for(int q_ = 0; q_ < 4; ++q_){                                             \
      const int idx_ = q_*256 + tid;                                           \
      const int g_ = idx_ >> 6;                                                \
      const int kd_ = idx_ & 63;                                               \
      const float* srcB_ = Bn + (size_t)g_*MEMIN + (kk)                        \
                           + ((((kd_ >> 3) ^ (g_ & 7)) << 3) + (kd_ & 7));     \
      gl_lds4(srcB_, &Bbuf[bb][q_*256 + wv*64]);                               \
    }                                                                          \
  }while(0)

  f32x4 acc0 = {0.f,0.f,0.f,0.f};
  f32x4 acc1 = {0.f,0.f,0.f,0.f};

  STAGE5(0, kbeg);                               // 8 vmem ops
  if(nsteps > 1) STAGE5(1, kbeg + KSTEP);        // 8 more, stay in flight

  int b = 0;
  for(int t = 0; t < nsteps; ++t){
    if(t < nsteps - 1){
      asm volatile("s_waitcnt vmcnt(8)" ::: "memory");   // stage(t) done
    } else {
      asm volatile("s_waitcnt vmcnt(0)" ::: "memory");
    }
    __builtin_amdgcn_s_barrier();
    #pragma unroll
    for(int s = 0; s < 2; ++s){
      const int jb = (s*4 + lg) ^ (lr & 7);
      const float* bp = &Bbuf[b][lr*64 + jb*8];
      const f32x4 blo = *(const f32x4*)bp;
      const f32x4 bhi = *(const f32x4*)(bp + 4);
      short8v bf;
      unsigned* u = (unsigned*)&bf;
      u[0] = pkbf(blo.x, blo.y); u[1] = pkbf(blo.z, blo.w);
      u[2] = pkbf(bhi.x, bhi.y); u[3] = pkbf(bhi.z, bhi.w);
      const short8v a0 = *(const short8v*)&Abuf[b][(wv*32 + lr)*64 + jb*8];
      const short8v a1 = *(const short8v*)&Abuf[b][(wv*32 + 16 + lr)*64 + jb*8];
      acc0 = __builtin_amdgcn_mfma_f32_16x16x32_bf16(a0, bf, acc0, 0, 0, 0);
      acc1 = __builtin_amdgcn_mfma_f32_16x16x32_bf16(a1, bf, acc1, 0, 0, 0);
    }
    __builtin_amdgcn_s_barrier();                // all waves done reading buf[b]
    if(t + 2 < nsteps) STAGE5(b, kbeg + (t+2)*KSTEP);
    b ^= 1;
  }
#undef STAGE5

  float* dst = xg4 + (size_t)ks*XGN;
  const int c0 = g0 + lr;
  const int r0 = wv*32 + lg*4, r1 = r0 + 16;
  #pragma unroll
  for(int j = 0; j < 4; ++j){
    dst[(size_t)((r0 + j)*8 + n)*G4H + c0] = acc0[j];
    dst[(size_t)((r1 + j)*8 + n)*G4H + c0] = acc1[j];
  }
}

// ---------------------------------------------------------------------------
// LSTM v2: 64 blocks = (b,n) pairs, 512 threads = gate-row g.  Whh row held
// packed-bf16 in 64 VGPRs (loaded once).  Per step: sum 4 K-split xg buffers
// + bias, dot over broadcast h (LDS), activations by threads<128.
// ---------------------------------------------------------------------------
__global__ __launch_bounds__(512) void k_lstm2(
    const float* __restrict__ xg4, const float* __restrict__ Whh,
    const float* __restrict__ bih, const float* __restrict__ bhh,
    float* __restrict__ out)
{
  __shared__ float hS[128];
  __shared__ float preS[512];
  const int bn = blockIdx.x;
  const int n = bn & 7, b = bn >> 3;
  const int g = threadIdx.x;

  unsigned wr[64];
  const float* wrow = Whh + (size_t)(n*G4H + g)*H_;
  #pragma unroll
  for(int i = 0; i < 32; ++i){
    const f32x4 w = *(const f32x4*)(wrow + i*4);
    wr[2*i]   = pkbf(w.x, w.y);
    wr[2*i+1] = pkbf(w.z, w.w);
  }
  const float bias = bih[n*G4H + g] + bhh[n*G4H + g];
  if(g < 128) hS[g] = 0.f;
  float cc = 0.f;
  __syncthreads();

  for(int t = 0; t < 16; ++t){
    const size_t xb = (size_t)((t*8 + b)*8 + n)*G4H + g;
    float acc = bias + xg4[xb] + xg4[xb + XGN] + xg4[xb + 2*XGN] + xg4[xb + 3*XGN];
    #pragma unroll
    for(int q = 0; q < 32; ++q){
      const f32x4 hv = *(const f32x4*)&hS[q*4];
      const unsigned w0 = wr[2*q], w1 = wr[2*q+1];
      acc += hv.x*bflo(w0) + hv.y*bfhi(w0) + hv.z*bflo(w1) + hv.w*bfhi(w1);
    }
    preS[g] = acc;
    __syncthreads();
    if(g < 128){
      const float iv = sigf(preS[g]);
      const float fv = sigf(preS[128 + g]);
      const float gv = tanhf(preS[256 + g]);
      const float ov = sigf(preS[384 + g]);
      cc = fv*cc + iv*gv;
      const float hn = ov*tanhf(cc);
      hS[g] = hn;
      out[(t*8 + b)*1024 + n*128 + g] = hn;
      if(t == 15){
        out[131072 + (b*8 + n)*128 + g] = hn;   // hT
        out[139264 + (b*8 + n)*128 + g] = cc;   // cT
      }
    }
    __syncthreads();
  }
}

// ---------------------------------------------------------------------------
// Tier-B fallbacks (round-3 verified): conv v1 + bias init + atomic MFMA gemm
// + old lstm
// ---------------------------------------------------------------------------
__global__ __launch_bounds__(512) void k_conv(
    const float* __restrict__ img, const float* __restrict__ gate,
    const float* __restrict__ cw, const float* __restrict__ cb,
    const float* __restrict__ sh, const float* __restrict__ tar,
    unsigned short* __restrict__ mem)
{
  __shared__ float imgS[8192];
  __shared__ float cwgS[1024];
  __shared__ float shS[128];
  __shared__ float tarS[160];
  const int tb = blockIdx.x, tid = threadIdx.x;
  for(int i = tid; i < 8192; i += 512)
    imgS[i] = img[(size_t)tb*8192 + i];
  if(tid < 128) shS[tid] = sh[tid];
  if(tid >= 128 && tid < 273) tarS[tid-128] = tar[tb*TAR_ + tid - 128];
  for(int n = 0; n < 8; ++n){
    __syncthreads();
    for(int i = tid; i < 1024; i += 512)
      cwgS[i] = cw[i] * gate[(tb*8 + n)*32 + (i & 31)];
    __syncthreads();
    unsigned short* mrow = mem + (size_t)(n*128 + tb)*AK;
    for(int q = 0; q < 4; ++q){
      const int idx = q*2048 + tid*4;
      const int d = idx >> 8, hw = idx & 255;
      const float bias = cb[d];
      float a0 = bias, a1 = bias, a2 = bias, a3 = bias;
      const float* cg = &cwgS[d*32];
      #pragma unroll
      for(int c = 0; c < 32; ++c){
        const f32x4 iv = *(const f32x4*)&imgS[c*256 + hw];
        const float w = cg[c];
        a0 += w*iv.x; a1 += w*iv.y; a2 += w*iv.z; a3 += w*iv.w;
      }
      ushort4 o;
      o.x = f2bf(a0); o.y = f2bf(a1); o.z = f2bf(a2); o.w = f2bf(a3);
      *(ushort4*)&mrow[idx] = o;
    }
    if(tid < 128)      mrow[8192 + tid]       = f2bf(shS[tid]);
    else if(tid < 273) mrow[8320 + tid - 128] = f2bf(tarS[tid - 128]);
    else if(tid < 320) mrow[8465 + tid - 273] = 0;   // zeros to 8512
  }
}

__global__ __launch_bounds__(256) void k_bias(const float* __restrict__ bih,
                                              const float* __restrict__ bhh,
                                              float* __restrict__ xg){
  const int i = blockIdx.x*256 + threadIdx.x;
  const int ng = ((i >> 9) & 7)*512 + (i & 511);
  xg[i] = bih[ng] + bhh[ng];
}

__global__ __launch_bounds__(256) void k_gemm_mfma(
    const unsigned short* __restrict__ mem, const float* __restrict__ Wih,
    float* __restrict__ xg)
{
  const int gt = blockIdx.x, n = blockIdx.y, ks = blockIdx.z;
  const int wv = threadIdx.x >> 6, ln = threadIdx.x & 63;
  const int lr = ln & 15, lg = ln >> 4;
  const int g0 = gt*16;
  const int kbeg = (ks==0) ? 0 : (ks==1) ? 2144 : (ks==2) ? 4256 : 6368;
  const int kend = (ks==0) ? 2144 : (ks==1) ? 4256 : (ks==2) ? 6368 : 8480;
  const float* Bp = Wih + (size_t)(n*G4H + g0 + lr)*MEMIN + lg*8;
  const unsigned short* Ap = mem + (size_t)(n*128 + wv*32 + lr)*AK + lg*8;
  f32x4 acc0 = {0.f,0.f,0.f,0.f};
  f32x4 acc1 = {0.f,0.f,0.f,0.f};
  #pragma unroll 2
  for(int k = kbeg; k < kend; k += 32){
    const f32x4u blo = *(const f32x4u*)(Bp + k);
    const f32x4u bhi = *(const f32x4u*)(Bp + k + 4);
    short8v bf;
    unsigned* bu = (unsigned*)&bf;
    bu[0] = pkbf(blo.x, blo.y); bu[1] = pkbf(blo.z, blo.w);
    bu[2] = pkbf(bhi.x, bhi.y); bu[3] = pkbf(bhi.z, bhi.w);
    const short8v a0 = *(const short8v*)(Ap + k);
    const short8v a1 = *(const short8v*)(Ap + (size_t)16*AK + k);
    acc0 = __builtin_amdgcn_mfma_f32_16x16x32_bf16(a0, bf, acc0, 0, 0, 0);
    acc1 = __builtin_amdgcn_mfma_f32_16x16x32_bf16(a1, bf, acc1, 0, 0, 0);
  }
  const int col = g0 + lr;
  const int r0  = wv*32 + lg*4;
  #pragma unroll
  for(int j = 0; j < 4; ++j){
    atomicAdd(&xg[(size_t)((r0 + j)*8 + n)*G4H + col],      acc0[j]);
    atomicAdd(&xg[(size_t)((r0 + 16 + j)*8 + n)*G4H + col], acc1[j]);
  }
}

__global__ __launch_bounds__(1024) void k_lstm(
    const float* __restrict__ xg, const float* __restrict__ Whh,
    float* __restrict__ out)
{
  extern __shared__ char smem[];
  unsigned short* Wl = (unsigned short*)smem;
  float* hS = (float*)(smem + 512*136*sizeof(unsigned short));

  const int n = blockIdx.x, tid = threadIdx.x;
  for(int i = tid; i < 512*128; i += 1024){
    int g = i >> 7, k = i & 127;
    Wl[g*136 + k] = f2bf(Whh[n*512*128 + i]);
  }
  hS[tid] = 0.f;
  const int h = tid >> 3, b = tid & 7;
  float cc = 0.f;
  __syncthreads();

  for(int t = 0; t < 16; ++t){
    const long xbase = ((long)((t*8 + b)*8 + n))*G4H + h;
    float g0 = xg[xbase + 0*128];
    float g1 = xg[xbase + 1*128];
    float g2 = xg[xbase + 2*128];
    float g3 = xg[xbase + 3*128];
    const float* hr = &hS[b*128];
    const unsigned short* w0 = &Wl[(0*128 + h)*136];
    const unsigned short* w1 = &Wl[(1*128 + h)*136];
    const unsigned short* w2 = &Wl[(2*128 + h)*136];
    const unsigned short* w3 = &Wl[(3*128 + h)*136];
    for(int k = 0; k < 128; k += 4){
      const float4 hv = *(const float4*)&hr[k];
      const ushort4 a0 = *(const ushort4*)&w0[k];
      const ushort4 a1 = *(const ushort4*)&w1[k];
      const ushort4 a2 = *(const ushort4*)&w2[k];
      const ushort4 a3 = *(const ushort4*)&w3[k];
      g0 += hv.x*bf2f(a0.x) + hv.y*bf2f(a0.y) + hv.z*bf2f(a0.z) + hv.w*bf2f(a0.w);
      g1 += hv.x*bf2f(a1.x) + hv.y*bf2f(a1.y) + hv.z*bf2f(a1.z) + hv.w*bf2f(a1.w);
      g2 += hv.x*bf2f(a2.x) + hv.y*bf2f(a2.y) + hv.z*bf2f(a2.z) + hv.w*bf2f(a2.w);
      g3 += hv.x*bf2f(a3.x) + hv.y*bf2f(a3.y) + hv.z*bf2f(a3.z) + hv.w*bf2f(a3.w);
    }
    const float iv = sigf(g0);
    const float fv = sigf(g1);
    const float gv = tanhf(g2);
    const float ov = sigf(g3);
    cc = fv*cc + iv*gv;
    const float hn = ov * tanhf(cc);
    __syncthreads();
    hS[b*128 + h] = hn;
    out[(t*8 + b)*1024 + n*128 + h] = hn;
    if(t == 15){
      out[131072 + (b*8 + n)*128 + h] = hn;
      out[139264 + (b*8 + n)*128 + h] = cc;
    }
    __syncthreads();
  }
}

// ---------------------------------------------------------------------------
// Tier-C fallback (round-2 verified, no extra ws): fused VALU gemm
// ---------------------------------------------------------------------------
__global__ __launch_bounds__(256) void k_gemm_old(
    const float* __restrict__ img, const float* __restrict__ gate,
    const float* __restrict__ cw, const float* __restrict__ cb,
    const float* __restrict__ sh, const float* __restrict__ tar,
    const float* __restrict__ Wih, const float* __restrict__ bih,
    const float* __restrict__ bhh, float* __restrict__ xg)
{
  __shared__ __align__(16) float imgS[16*545];
  __shared__ __align__(16) float WtS[16*132];
  __shared__ float PS[16*17];
  __shared__ float gateS[16*32];
  __shared__ float cw2S[16*32];
  __shared__ float cwS[32*32];
  __shared__ float cbS[32];
  __shared__ float shS[128];
  __shared__ float tarS[16*145];

  const int tid = threadIdx.x;
  const int g0  = blockIdx.x * 128;
  const int tb0 = blockIdx.y * 16;
  const int n   = blockIdx.z;
  const int gth = tid & 31;
  const int rth = tid >> 5;
  const long wbase = (long)(n*G4H + g0) * MEMIN;

  for(int i = tid; i < 16*32; i += 256){
    int r = i >> 5, c = i & 31;
    gateS[i] = gate[((tb0 + r)*N_ + n)*C_ + c];
  }
  for(int i = tid; i < 32*32; i += 256) cwS[i] = cw[i];
  if(tid < 32)  cbS[tid] = cb[tid];
  if(tid < 128) shS[tid] = sh[tid];
  for(int i = tid; i < 16*TAR_; i += 256)
    tarS[i] = tar[tb0*TAR_ + i];

  float acc0[4] = {0,0,0,0}, acc1[4] = {0,0,0,0};

  for(int s = 0; s < 16; ++s){
    __syncthreads();
    for(int i = tid; i < 8192; i += 256){
      int j = i & 15, c = (i >> 4) & 31, r = i >> 9;
      imgS[r*545 + c*17 + j] = img[((tb0 + r)*C_ + c)*HW_ + s*16 + j];
    }
    for(int d = 0; d < 32; ++d){
      __syncthreads();
      for(int i = tid; i < 2048; i += 256){
        int g = i >> 4, j = i & 15;
        WtS[j*132 + g] = Wih[wbase + (long)g*MEMIN + d*HW_ + s*16 + j];
      }
      for(int i = tid; i < 512; i += 256)
        cw2S[i] = gateS[i] * cwS[d*32 + (i & 31)];
      __syncthreads();
      {
        int j = tid & 15, r = tid >> 4;
        float a = cbS[d];
        const float* c2 = &cw2S[r*32];
        const float* im = &imgS[r*545 + j];
        #pragma unroll
        for(int c = 0; c < 32; ++c) a += c2[c] * im[c*17];
        PS[j*17 + r] = a;
      }
      __syncthreads();
      #pragma unroll
      for(int j = 0; j < 16; ++j){
        const float4 w = *(const float4*)&WtS[j*132 + (gth << 2)];
        const float p0 = PS[j*17 + (rth << 1)];
        const float p1 = PS[j*17 + (rth << 1) + 1];
        acc0[0] += p0*w.x; acc0[1] += p0*w.y; acc0[2] += p0*w.z; acc0[3] += p0*w.w;
        acc1[0] += p1*w.x; acc1[1] += p1*w.y; acc1[2] += p1*w.z; acc1[3] += p1*w.w;
      }
    }
  }
  {
    float ta[4] = {0,0,0,0};
    for(int kc = 0; kc < 8; ++kc){
      __syncthreads();
      for(int i = tid; i < 2048; i += 256){
        int g = i >> 4, j = i & 15;
        WtS[j*132 + g] = Wih[wbase + (long)g*MEMIN + 8192 + kc*16 + j];
      }
      __syncthreads();
      #pragma unroll
      for(int j = 0; j < 16; ++j){
        const float4 w = *(const float4*)&WtS[j*132 + (gth << 2)];
        const float sv = shS[kc*16 + j];
        ta[0] += sv*w.x; ta[1] += sv*w.y; ta[2] += sv*w.z; ta[3] += sv*w.w;
      }
    }
    acc0[0] += ta[0]; acc0[1] += ta[1]; acc0[2] += ta[2]; acc0[3] += ta[3];
    acc1[0] += ta[0]; acc1[1] += ta[1]; acc1[2] += ta[2]; acc1[3] += ta[3];
  }
  for(int kc = 0; kc < 10; ++kc){
    const int kendl = (kc == 9) ? 1 : 16;
    __syncthreads();
    for(int i = tid; i < 2048; i += 256){
      int g = i >> 4, j = i & 15;
      if(j < kendl)
        WtS[j*132 + g] = Wih[wbase + (long)g*MEMIN + 8320 + kc*16 + j];
    }
    __syncthreads();
    for(int j = 0; j < kendl; ++j){
      const float4 w = *(const float4*)&WtS[j*132 + (gth << 2)];
      const float p0 = tarS[(rth << 1)*TAR_ + kc*16 + j];
      const float p1 = tarS[((rth << 1) + 1)*TAR_ + kc*16 + j];
      acc0[0] += p0*w.x; acc0[1] += p0*w.y; acc0[2] += p0*w.z; acc0[3] += p0*w.w;
      acc1[0] += p1*w.x; acc1[1] += p1*w.y; acc1[2] += p1*w.z; acc1[3] += p1*w.w;
    }
  }
  {
    const int gg = g0 + (gth << 2);
    const float b0 = bih[n*G4H + gg + 0] + bhh[n*G4H + gg + 0];
    const float b1 = bih[n*G4H + gg + 1] + bhh[n*G4H + gg + 1];
    const float b2 = bih[n*G4H + gg + 2] + bhh[n*G4H + gg + 2];
    const float b3 = bih[n*G4H + gg + 3] + bhh[n*G4H + gg + 3];
    const int row = tb0 + (rth << 1);
    float4 o0 = make_float4(acc0[0]+b0, acc0[1]+b1, acc0[2]+b2, acc0[3]+b3);
    *(float4*)&xg[((long)(row*N_ + n))*G4H + gg] = o0;
    float4 o1 = make_float4(acc1[0]+b0, acc1[1]+b1, acc1[2]+b2, acc1[3]+b3);
    *(float4*)&xg[((long)((row + 1)*N_ + n))*G4H + gg] = o1;
  }
}

// ---------------------------------------------------------------------------
extern "C" void kernel_launch(void* const* d_in, const int* in_sizes, int n_in,
                              void* d_out, int out_size, void* d_ws, size_t ws_size,
                              hipStream_t stream)
{
  (void)in_sizes; (void)n_in; (void)out_size;
  const float* img  = (const float*)d_in[0];
  const float* tar  = (const float*)d_in[1];
  const float* WvB  = (const float*)d_in[7];
  const float* WoW  = (const float*)d_in[8];
  const float* WoB  = (const float*)d_in[9];
  const float* tdw  = (const float*)d_in[10];
  const float* tdb  = (const float*)d_in[11];
  const float* cw   = (const float*)d_in[12];
  const float* cb   = (const float*)d_in[13];
  const float* Wih  = (const float*)d_in[14];
  const float* Whh  = (const float*)d_in[15];
  const float* bih  = (const float*)d_in[16];
  const float* bhh  = (const float*)d_in[17];

  float* wsf   = (float*)d_ws;
  float* gatew = wsf;                       // 32768 f
  float* shw   = wsf + 32768;               // 128 f

  // Tier A layout: xg4 @ f32[32896..2130048) (4 x 524288), mem @ byte 8520192
  float* xg4w = wsf + 32896;
  unsigned short* memA = (unsigned short*)((char*)d_ws + 8520192);
  const size_t WS_A = 8520192 + (size_t)8*128*AK*2;          // 25,952,768 B

  // Tier B layout (round-3): xg @ f32[32896..557184), mem @ byte 2228736
  float* xgB = wsf + 32896;
  unsigned short* memB = (unsigned short*)((char*)d_ws + 2228736);
  const size_t WS_B = 2228736 + (size_t)8*128*AK*2;          // 19,661,312 B

  k_shared<<<128, 64, 0, stream>>>(WvB, WoW, WoB, shw);
  k_gate<<<dim3(8, 8), 256, 0, stream>>>(tar, tdw, tdb, gatew);

  if(ws_size >= WS_A){
    k_conv2<<<dim3(128, 8), 256, 0, stream>>>(img, gatew, cw, cb, shw, tar, memA);
    k_gemm5<<<dim3(32, 8, 4), 256, 0, stream>>>(memA, Wih, xg4w);
    k_lstm2<<<64, 512, 0, stream>>>(xg4w, Whh, bih, bhh, (float*)d_out);
  } else if(ws_size >= WS_B){
    k_conv<<<128, 512, 0, stream>>>(img, gatew, cw, cb, shw, tar, memB);
    k_bias<<<2048, 256, 0, stream>>>(bih, bhh, xgB);
    k_gemm_mfma<<<dim3(32, 8, 4), 256, 0, stream>>>(memB, Wih, xgB);
    (void)hipFuncSetAttribute((const void*)k_lstm,
                              hipFuncAttributeMaxDynamicSharedMemorySize, 143360);
    k_lstm<<<8, 1024, 143360, stream>>>(xgB, Whh, (float*)d_out);
  } else {
    k_gemm_old<<<dim3(4, 8, 8), 256, 0, stream>>>(img, gatew, cw, cb, shw, tar,
                                                  Wih, bih, bhh, xgB);
    (void)hipFuncSetAttribute((const void*)k_lstm,
                              hipFuncAttributeMaxDynamicSharedMemorySize, 143360);
    k_lstm<<<8, 1024, 143360, stream>>>(xgB, Whh, (float*)d_out);
  }
}